// Round 1
// baseline (4984.873 us; speedup 1.0000x reference)
//
#include <hip/hip_runtime.h>

// ---------------------------------------------------------------------------
// Encoder: x = feats@W_aff + b_aff ; xw = x@W_gcn  (folded: xw = feats@Wc + bc)
// GCN aggregate with self loops + symmetric norm -> embedding (written to d_out)
// pred: t = [emb[s], emb[o]]@W_pred_in + b_pred_in ; w = t@W_pred_out + b_pred_out
// (final dot fused into pred-GEMM epilogue)
// ---------------------------------------------------------------------------

__global__ void degree_kernel(const int* __restrict__ src, const int* __restrict__ dst,
                              unsigned* __restrict__ outd, unsigned* __restrict__ ind, int E) {
    int e = blockIdx.x * blockDim.x + threadIdx.x;
    if (e < E) {
        atomicAdd(&outd[src[e]], 1u);
        atomicAdd(&ind[dst[e]], 1u);
    }
}

__global__ void norm_kernel(const unsigned* __restrict__ outd, const unsigned* __restrict__ ind,
                            float* __restrict__ ns, float* __restrict__ nd, int N) {
    int i = blockIdx.x * blockDim.x + threadIdx.x;
    if (i < N) {
        ns[i] = rsqrtf((float)(outd[i] + 1u));   // +1 self loop; always > 0
        nd[i] = rsqrtf((float)(ind[i] + 1u));
    }
}

// bc[n] = sum_k b_aff[k] * W_gcn[k*D + n]
__global__ void bcomb_kernel(const float* __restrict__ b_aff, const float* __restrict__ W_gcn,
                             float* __restrict__ bc, int D) {
    int n = blockIdx.x * blockDim.x + threadIdx.x;
    if (n < D) {
        float s = 0.f;
        for (int k = 0; k < D; ++k) s = fmaf(b_aff[k], W_gcn[k * D + n], s);
        bc[n] = s;
    }
}

// ---------------------------------------------------------------------------
// Generic fp32 tiled GEMM: C[M,N] = A[M,K] @ B[K,N] (+ bias[n])
// BM=BN=64, BK=16, 256 threads, 4x4 micro-tile.
// ---------------------------------------------------------------------------
template <bool HAS_BIAS>
__global__ __launch_bounds__(256) void sgemm_kernel(const float* __restrict__ A, int lda,
                                                    const float* __restrict__ B, int ldb,
                                                    const float* __restrict__ bias,
                                                    float* __restrict__ C, int ldc,
                                                    int M, int N, int K) {
    __shared__ __align__(16) float As[16][68];   // [k][m]
    __shared__ __align__(16) float Bs[16][68];   // [k][n]
    const int tid = threadIdx.x;
    const int tx = tid & 15, ty = tid >> 4;
    const int row0 = blockIdx.x * 64;
    const int col0 = blockIdx.y * 64;

    const int a_row = tid >> 2;        // 0..63
    const int a_k   = (tid & 3) * 4;   // 0,4,8,12
    const int b_k   = tid >> 4;        // 0..15
    const int b_c   = (tid & 15) * 4;  // 0..60

    float acc[4][4] = {};

    for (int k0 = 0; k0 < K; k0 += 16) {
        // --- load A tile (zero-padded OOB) ---
        float4 av = make_float4(0.f, 0.f, 0.f, 0.f);
        {
            int gr = row0 + a_row;
            int gk = k0 + a_k;
            if (gr < M) {
                if (gk + 3 < K) {
                    av = *reinterpret_cast<const float4*>(&A[(long)gr * lda + gk]);
                } else {
                    float t0 = (gk + 0 < K) ? A[(long)gr * lda + gk + 0] : 0.f;
                    float t1 = (gk + 1 < K) ? A[(long)gr * lda + gk + 1] : 0.f;
                    float t2 = (gk + 2 < K) ? A[(long)gr * lda + gk + 2] : 0.f;
                    float t3 = (gk + 3 < K) ? A[(long)gr * lda + gk + 3] : 0.f;
                    av = make_float4(t0, t1, t2, t3);
                }
            }
        }
        // --- load B tile (zero-padded OOB) ---
        float4 bv = make_float4(0.f, 0.f, 0.f, 0.f);
        {
            int gk = k0 + b_k;
            int gc = col0 + b_c;
            if (gk < K) {
                if (gc + 3 < N) {
                    bv = *reinterpret_cast<const float4*>(&B[(long)gk * ldb + gc]);
                } else {
                    float t0 = (gc + 0 < N) ? B[(long)gk * ldb + gc + 0] : 0.f;
                    float t1 = (gc + 1 < N) ? B[(long)gk * ldb + gc + 1] : 0.f;
                    float t2 = (gc + 2 < N) ? B[(long)gk * ldb + gc + 2] : 0.f;
                    float t3 = (gc + 3 < N) ? B[(long)gk * ldb + gc + 3] : 0.f;
                    bv = make_float4(t0, t1, t2, t3);
                }
            }
        }
        __syncthreads();   // protect previous iteration's reads
        As[a_k + 0][a_row] = av.x;
        As[a_k + 1][a_row] = av.y;
        As[a_k + 2][a_row] = av.z;
        As[a_k + 3][a_row] = av.w;
        *reinterpret_cast<float4*>(&Bs[b_k][b_c]) = bv;
        __syncthreads();

#pragma unroll
        for (int k = 0; k < 16; ++k) {
            const float4 a = *reinterpret_cast<const float4*>(&As[k][ty * 4]);
            const float4 b = *reinterpret_cast<const float4*>(&Bs[k][tx * 4]);
            const float avv[4] = {a.x, a.y, a.z, a.w};
            const float bvv[4] = {b.x, b.y, b.z, b.w};
#pragma unroll
            for (int i = 0; i < 4; ++i)
#pragma unroll
                for (int j = 0; j < 4; ++j)
                    acc[i][j] = fmaf(avv[i], bvv[j], acc[i][j]);
        }
    }

#pragma unroll
    for (int i = 0; i < 4; ++i) {
        int r = row0 + ty * 4 + i;
        if (r >= M) continue;
#pragma unroll
        for (int j = 0; j < 4; ++j) {
            int c = col0 + tx * 4 + j;
            if (c < N) {
                float v = acc[i][j];
                if (HAS_BIAS) v += bias[c];
                C[(long)r * ldc + c] = v;
            }
        }
    }
}

// ---------------------------------------------------------------------------
// Message scatter: for each edge e (and self loops): emb[dst] += xw[src]*norm_src[src]
// ---------------------------------------------------------------------------
__global__ void scatter_kernel(const float* __restrict__ xw, const int* __restrict__ src,
                               const int* __restrict__ dst, const float* __restrict__ ns,
                               float* __restrict__ emb, int E, int D) {
    int e = blockIdx.x;
    int s, d;
    if (e < E) { s = src[e]; d = dst[e]; }
    else       { s = d = e - E; }
    float c = ns[s];
    const float* xr = xw + (long)s * D;
    float* er = emb + (long)d * D;
    for (int i = threadIdx.x; i < D; i += blockDim.x)
        atomicAdd(&er[i], xr[i] * c);
}

// emb[i][d] = emb[i][d] * nd[i] + b_gcn[d]   (float4-vectorized, D % 4 == 0)
__global__ void finalize_kernel(float* __restrict__ emb, const float* __restrict__ nd,
                                const float* __restrict__ b_gcn, int N, int D) {
    long idx = (long)blockIdx.x * blockDim.x + threadIdx.x;
    long total = (long)N * D / 4;
    if (idx >= total) return;
    long flat = idx * 4;
    int node = (int)(flat / D);
    int col  = (int)(flat - (long)node * D);
    float4 v = *reinterpret_cast<const float4*>(&emb[flat]);
    float4 b = *reinterpret_cast<const float4*>(&b_gcn[col]);
    float s = nd[node];
    v.x = fmaf(v.x, s, b.x);
    v.y = fmaf(v.y, s, b.y);
    v.z = fmaf(v.z, s, b.z);
    v.w = fmaf(v.w, s, b.w);
    *reinterpret_cast<float4*>(&emb[flat]) = v;
}

__global__ void initw_kernel(float* __restrict__ w, const float* __restrict__ b, int T) {
    int i = blockIdx.x * blockDim.x + threadIdx.x;
    if (i < T) w[i] = b[0];
}

// ---------------------------------------------------------------------------
// Fused pred GEMM: A row r = concat(emb[trip[r][0]], emb[trip[r][2]]) (K=2*D)
// t = A @ W_pred_in + b_pred_in, then weights[r] += sum_c t[r][c]*W_pred_out[c]
// (atomicAdd partials per col-block). T % 64 == 0 assumed for rows.
// ---------------------------------------------------------------------------
__global__ __launch_bounds__(256) void pred_gemm_kernel(
    const float* __restrict__ emb, const int* __restrict__ trip,
    const float* __restrict__ B, const float* __restrict__ b_in,
    const float* __restrict__ w_out, float* __restrict__ weights,
    int T, int D, int K /* = 2*D */) {
    __shared__ __align__(16) float As[16][68];
    __shared__ __align__(16) float Bs[16][68];
    __shared__ int ls[64];
    __shared__ int lo[64];
    __shared__ float red[64][17];

    const int tid = threadIdx.x;
    const int tx = tid & 15, ty = tid >> 4;
    const int row0 = blockIdx.x * 64;
    const int col0 = blockIdx.y * 64;
    const int N = D;  // output cols of pred_in

    if (tid < 64) {
        int r = row0 + tid;
        ls[tid] = trip[r * 3 + 0];
        lo[tid] = trip[r * 3 + 2];
    }
    __syncthreads();

    const int a_row = tid >> 2;
    const int a_k   = (tid & 3) * 4;
    const int b_k   = tid >> 4;
    const int b_c   = (tid & 15) * 4;

    float acc[4][4] = {};

    for (int k0 = 0; k0 < K; k0 += 16) {
        float4 av = make_float4(0.f, 0.f, 0.f, 0.f);
        {
            int gk = k0 + a_k;
            if (gk + 3 < K) {
                // which half of the concat (D % 4 == 0 so a float4 never straddles)
                int node = (gk < D) ? ls[a_row] : lo[a_row];
                int col  = (gk < D) ? gk : gk - D;
                av = *reinterpret_cast<const float4*>(&emb[(long)node * D + col]);
            } else if (gk < K) {
                int node = (gk < D) ? ls[a_row] : lo[a_row];
                int col  = (gk < D) ? gk : gk - D;
                const float* p = &emb[(long)node * D + col];
                float t0 = (gk + 0 < K) ? p[0] : 0.f;
                float t1 = (gk + 1 < K) ? p[1] : 0.f;
                float t2 = (gk + 2 < K) ? p[2] : 0.f;
                float t3 = (gk + 3 < K) ? p[3] : 0.f;
                av = make_float4(t0, t1, t2, t3);
            }
        }
        float4 bv = make_float4(0.f, 0.f, 0.f, 0.f);
        {
            int gk = k0 + b_k;
            int gc = col0 + b_c;
            if (gk < K) {
                if (gc + 3 < N) {
                    bv = *reinterpret_cast<const float4*>(&B[(long)gk * N + gc]);
                } else {
                    float t0 = (gc + 0 < N) ? B[(long)gk * N + gc + 0] : 0.f;
                    float t1 = (gc + 1 < N) ? B[(long)gk * N + gc + 1] : 0.f;
                    float t2 = (gc + 2 < N) ? B[(long)gk * N + gc + 2] : 0.f;
                    float t3 = (gc + 3 < N) ? B[(long)gk * N + gc + 3] : 0.f;
                    bv = make_float4(t0, t1, t2, t3);
                }
            }
        }
        __syncthreads();
        As[a_k + 0][a_row] = av.x;
        As[a_k + 1][a_row] = av.y;
        As[a_k + 2][a_row] = av.z;
        As[a_k + 3][a_row] = av.w;
        *reinterpret_cast<float4*>(&Bs[b_k][b_c]) = bv;
        __syncthreads();

#pragma unroll
        for (int k = 0; k < 16; ++k) {
            const float4 a = *reinterpret_cast<const float4*>(&As[k][ty * 4]);
            const float4 b = *reinterpret_cast<const float4*>(&Bs[k][tx * 4]);
            const float avv[4] = {a.x, a.y, a.z, a.w};
            const float bvv[4] = {b.x, b.y, b.z, b.w};
#pragma unroll
            for (int i = 0; i < 4; ++i)
#pragma unroll
                for (int j = 0; j < 4; ++j)
                    acc[i][j] = fmaf(avv[i], bvv[j], acc[i][j]);
        }
    }

    // Epilogue: p[i] = sum_j (acc[i][j] + b_in[c]) * w_out[c]  for valid cols
    float p[4] = {0.f, 0.f, 0.f, 0.f};
#pragma unroll
    for (int j = 0; j < 4; ++j) {
        int c = col0 + tx * 4 + j;
        if (c < N) {
            float bi = b_in[c];
            float wo = w_out[c];
#pragma unroll
            for (int i = 0; i < 4; ++i)
                p[i] = fmaf(acc[i][j] + bi, wo, p[i]);
        }
    }
    __syncthreads();
#pragma unroll
    for (int i = 0; i < 4; ++i) red[ty * 4 + i][tx] = p[i];
    __syncthreads();
    if (tid < 64) {
        float s = 0.f;
#pragma unroll
        for (int j = 0; j < 16; ++j) s += red[tid][j];
        atomicAdd(&weights[row0 + tid], s);
    }
}

// ---------------------------------------------------------------------------

extern "C" void kernel_launch(void* const* d_in, const int* in_sizes, int n_in,
                              void* d_out, int out_size, void* d_ws, size_t ws_size,
                              hipStream_t stream) {
    const float* feats      = (const float*)d_in[0];
    const float* W_aff      = (const float*)d_in[1];
    const float* b_aff      = (const float*)d_in[2];
    const float* W_gcn      = (const float*)d_in[3];
    const float* b_gcn      = (const float*)d_in[4];
    const float* W_pred_in  = (const float*)d_in[5];
    const float* b_pred_in  = (const float*)d_in[6];
    const float* W_pred_out = (const float*)d_in[7];
    const float* b_pred_out = (const float*)d_in[8];
    const int*   src        = (const int*)d_in[9];
    const int*   dst        = (const int*)d_in[10];
    const int*   trip       = (const int*)d_in[11];

    const int D = in_sizes[2];           // 500
    const int F = in_sizes[1] / D;       // 128
    const int N = in_sizes[0] / F;       // 50000
    const int E = in_sizes[9];           // 800000
    const int T = in_sizes[11] / 3;      // 200000

    float* weights = (float*)d_out;          // [T]
    float* emb     = (float*)d_out + T;      // [N*D]

    // workspace layout (floats)
    float*    xw   = (float*)d_ws;                    // N*D
    float*    Wc   = xw + (size_t)N * D;              // F*D  (W_aff @ W_gcn)
    float*    bc   = Wc + (size_t)F * D;              // D    (b_aff @ W_gcn)
    float*    ns   = bc + D;                          // N
    float*    nd   = ns + N;                          // N
    unsigned* outd = (unsigned*)(nd + N);             // N
    unsigned* ind  = outd + N;                        // N

    // zero the accumulators we own
    hipMemsetAsync(outd, 0, 2 * (size_t)N * sizeof(unsigned), stream);
    hipMemsetAsync(emb, 0, (size_t)N * D * sizeof(float), stream);

    // degrees + norms
    degree_kernel<<<(E + 255) / 256, 256, 0, stream>>>(src, dst, outd, ind, E);
    norm_kernel<<<(N + 255) / 256, 256, 0, stream>>>(outd, ind, ns, nd, N);

    // Wc = W_aff @ W_gcn   (128 x 500 x 500)
    {
        dim3 grid((F + 63) / 64, (D + 63) / 64);
        sgemm_kernel<false><<<grid, 256, 0, stream>>>(W_aff, D, W_gcn, D, nullptr,
                                                      Wc, D, F, D, D);
    }
    bcomb_kernel<<<(D + 255) / 256, 256, 0, stream>>>(b_aff, W_gcn, bc, D);

    // xw = feats @ Wc + bc   (50000 x 128 x 500)
    {
        dim3 grid((N + 63) / 64, (D + 63) / 64);
        sgemm_kernel<true><<<grid, 256, 0, stream>>>(feats, F, Wc, D, bc,
                                                     xw, D, N, D, F);
    }

    // scatter messages (edges + self loops) into emb
    scatter_kernel<<<E + N, 128, 0, stream>>>(xw, src, dst, ns, emb, E, D);

    // emb = emb * nd + b_gcn
    {
        long total4 = (long)N * D / 4;
        finalize_kernel<<<(unsigned)((total4 + 255) / 256), 256, 0, stream>>>(emb, nd, b_gcn, N, D);
    }

    // weights init with output bias, then fused pred GEMM accumulates
    initw_kernel<<<(T + 255) / 256, 256, 0, stream>>>(weights, b_pred_out, T);
    {
        dim3 grid(T / 64, (D + 63) / 64);
        pred_gemm_kernel<<<grid, 256, 0, stream>>>(emb, trip, W_pred_in, b_pred_in,
                                                   W_pred_out, weights, T, D, 2 * D);
    }
}

// Round 2
// 2434.780 us; speedup vs baseline: 2.0474x; 2.0474x over previous
//
#include <hip/hip_runtime.h>

// ---------------------------------------------------------------------------
// Encoder: xw = feats@(W_aff@W_gcn) + (b_aff@W_gcn)   (affine folded into GCN)
// GCN aggregate with self loops + symmetric norm -> embedding (fp32, d_out)
// pred: weights = ([emb[s],emb[o]] @ W_pred_in + b_in) @ w_out + b_out
//   -> bf16 MFMA GEMM (K,N padded to 1024/512), final dot fused in epilogue,
//      bias chain folded to scalar bias_dot.
// ---------------------------------------------------------------------------

typedef float f32x4 __attribute__((ext_vector_type(4)));
typedef short s16x8 __attribute__((ext_vector_type(8)));

__device__ __forceinline__ unsigned short f2bf(float f) {
    unsigned u = __float_as_uint(f);
    unsigned r = (u + 0x7FFFu + ((u >> 16) & 1u)) >> 16;
    return (unsigned short)r;
}

__device__ __forceinline__ void async_ld16(const void* g, void* lds) {
    __builtin_amdgcn_global_load_lds(
        (const __attribute__((address_space(1))) unsigned int*)g,
        (__attribute__((address_space(3))) unsigned int*)lds,
        16, 0, 0);
}

// ---------------------------------------------------------------------------
__global__ void degree_kernel(const int* __restrict__ src, const int* __restrict__ dst,
                              unsigned* __restrict__ outd, unsigned* __restrict__ ind, int E) {
    int e = blockIdx.x * blockDim.x + threadIdx.x;
    if (e < E) {
        atomicAdd(&outd[src[e]], 1u);
        atomicAdd(&ind[dst[e]], 1u);
    }
}

__global__ void norm_kernel(const unsigned* __restrict__ outd, const unsigned* __restrict__ ind,
                            float* __restrict__ ns, float* __restrict__ nd, int N) {
    int i = blockIdx.x * blockDim.x + threadIdx.x;
    if (i < N) {
        ns[i] = rsqrtf((float)(outd[i] + 1u));   // +1 self loop; always > 0
        nd[i] = rsqrtf((float)(ind[i] + 1u));
    }
}

// bc[n] = sum_k b_aff[k] * W_gcn[k*D + n]
__global__ void bcomb_kernel(const float* __restrict__ b_aff, const float* __restrict__ W_gcn,
                             float* __restrict__ bc, int D) {
    int n = blockIdx.x * blockDim.x + threadIdx.x;
    if (n < D) {
        float s = 0.f;
        for (int k = 0; k < D; ++k) s = fmaf(b_aff[k], W_gcn[k * D + n], s);
        bc[n] = s;
    }
}

// ---------------------------------------------------------------------------
// Generic fp32 tiled GEMM (used for the small Wc and xw GEMMs)
// ---------------------------------------------------------------------------
template <bool HAS_BIAS>
__global__ __launch_bounds__(256) void sgemm_kernel(const float* __restrict__ A, int lda,
                                                    const float* __restrict__ B, int ldb,
                                                    const float* __restrict__ bias,
                                                    float* __restrict__ C, int ldc,
                                                    int M, int N, int K) {
    __shared__ __align__(16) float As[16][68];
    __shared__ __align__(16) float Bs[16][68];
    const int tid = threadIdx.x;
    const int tx = tid & 15, ty = tid >> 4;
    const int row0 = blockIdx.x * 64;
    const int col0 = blockIdx.y * 64;

    const int a_row = tid >> 2;
    const int a_k   = (tid & 3) * 4;
    const int b_k   = tid >> 4;
    const int b_c   = (tid & 15) * 4;

    float acc[4][4] = {};

    for (int k0 = 0; k0 < K; k0 += 16) {
        float4 av = make_float4(0.f, 0.f, 0.f, 0.f);
        {
            int gr = row0 + a_row;
            int gk = k0 + a_k;
            if (gr < M) {
                if (gk + 3 < K) {
                    av = *reinterpret_cast<const float4*>(&A[(long)gr * lda + gk]);
                } else {
                    float t0 = (gk + 0 < K) ? A[(long)gr * lda + gk + 0] : 0.f;
                    float t1 = (gk + 1 < K) ? A[(long)gr * lda + gk + 1] : 0.f;
                    float t2 = (gk + 2 < K) ? A[(long)gr * lda + gk + 2] : 0.f;
                    float t3 = (gk + 3 < K) ? A[(long)gr * lda + gk + 3] : 0.f;
                    av = make_float4(t0, t1, t2, t3);
                }
            }
        }
        float4 bv = make_float4(0.f, 0.f, 0.f, 0.f);
        {
            int gk = k0 + b_k;
            int gc = col0 + b_c;
            if (gk < K) {
                if (gc + 3 < N) {
                    bv = *reinterpret_cast<const float4*>(&B[(long)gk * ldb + gc]);
                } else {
                    float t0 = (gc + 0 < N) ? B[(long)gk * ldb + gc + 0] : 0.f;
                    float t1 = (gc + 1 < N) ? B[(long)gk * ldb + gc + 1] : 0.f;
                    float t2 = (gc + 2 < N) ? B[(long)gk * ldb + gc + 2] : 0.f;
                    float t3 = (gc + 3 < N) ? B[(long)gk * ldb + gc + 3] : 0.f;
                    bv = make_float4(t0, t1, t2, t3);
                }
            }
        }
        __syncthreads();
        As[a_k + 0][a_row] = av.x;
        As[a_k + 1][a_row] = av.y;
        As[a_k + 2][a_row] = av.z;
        As[a_k + 3][a_row] = av.w;
        *reinterpret_cast<float4*>(&Bs[b_k][b_c]) = bv;
        __syncthreads();

#pragma unroll
        for (int k = 0; k < 16; ++k) {
            const float4 a = *reinterpret_cast<const float4*>(&As[k][ty * 4]);
            const float4 b = *reinterpret_cast<const float4*>(&Bs[k][tx * 4]);
            const float avv[4] = {a.x, a.y, a.z, a.w};
            const float bvv[4] = {b.x, b.y, b.z, b.w};
#pragma unroll
            for (int i = 0; i < 4; ++i)
#pragma unroll
                for (int j = 0; j < 4; ++j)
                    acc[i][j] = fmaf(avv[i], bvv[j], acc[i][j]);
        }
    }

#pragma unroll
    for (int i = 0; i < 4; ++i) {
        int r = row0 + ty * 4 + i;
        if (r >= M) continue;
#pragma unroll
        for (int j = 0; j < 4; ++j) {
            int c = col0 + tx * 4 + j;
            if (c < N) {
                float v = acc[i][j];
                if (HAS_BIAS) v += bias[c];
                C[(long)r * ldc + c] = v;
            }
        }
    }
}

// ---------------------------------------------------------------------------
// Message scatter: emb[dst] += xw[src]*norm_src[src]  (edges + self loops)
// ---------------------------------------------------------------------------
__global__ void scatter_kernel(const float* __restrict__ xw, const int* __restrict__ src,
                               const int* __restrict__ dst, const float* __restrict__ ns,
                               float* __restrict__ emb, int E, int D) {
    int e = blockIdx.x;
    int s, d;
    if (e < E) { s = src[e]; d = dst[e]; }
    else       { s = d = e - E; }
    float c = ns[s];
    const float* xr = xw + (long)s * D;
    float* er = emb + (long)d * D;
    for (int i = threadIdx.x; i < D; i += blockDim.x)
        atomicAdd(&er[i], xr[i] * c);
}

// emb[i][d] = emb[i][d] * nd[i] + b_gcn[d]
__global__ void finalize_kernel(float* __restrict__ emb, const float* __restrict__ nd,
                                const float* __restrict__ b_gcn, int N, int D) {
    long idx = (long)blockIdx.x * blockDim.x + threadIdx.x;
    long total = (long)N * D / 4;
    if (idx >= total) return;
    long flat = idx * 4;
    int node = (int)(flat / D);
    int col  = (int)(flat - (long)node * D);
    float4 v = *reinterpret_cast<const float4*>(&emb[flat]);
    float4 b = *reinterpret_cast<const float4*>(&b_gcn[col]);
    float s = nd[node];
    v.x = fmaf(v.x, s, b.x);
    v.y = fmaf(v.y, s, b.y);
    v.z = fmaf(v.z, s, b.z);
    v.w = fmaf(v.w, s, b.w);
    *reinterpret_cast<float4*>(&emb[flat]) = v;
}

// ---------------------------------------------------------------------------
// bf16 conversion / padding kernels
// ---------------------------------------------------------------------------
// emb fp32 [N][D] -> emb16 bf16 [N][PD] (cols >= D zero)
__global__ void conv_emb_kernel(const float* __restrict__ emb, unsigned short* __restrict__ emb16,
                                int N, int D, int PD) {
    long idx = (long)blockIdx.x * blockDim.x + threadIdx.x;
    long total = (long)N * (PD / 4);
    if (idx >= total) return;
    int node = (int)(idx / (PD / 4));
    int c4 = (int)(idx - (long)node * (PD / 4)) * 4;
    ushort4 o = make_ushort4(0, 0, 0, 0);
    if (c4 + 3 < D) {
        float4 v = *reinterpret_cast<const float4*>(&emb[(long)node * D + c4]);
        o.x = f2bf(v.x); o.y = f2bf(v.y); o.z = f2bf(v.z); o.w = f2bf(v.w);
    } else if (c4 < D) {
        const float* p = &emb[(long)node * D + c4];
        unsigned short t[4] = {0, 0, 0, 0};
        for (int k = 0; k < 4; ++k) if (c4 + k < D) t[k] = f2bf(p[k]);
        o.x = t[0]; o.y = t[1]; o.z = t[2]; o.w = t[3];
    }
    *reinterpret_cast<ushort4*>(&emb16[(long)node * PD + c4]) = o;
}

// W_pred_in [2D][D] row-major -> Bt bf16 [PD cols][PK k] (transposed + split-pad)
// Bt[n][k]: k<PD -> srcrow=k (valid k<D); k>=PD -> srcrow=D+(k-PD) (valid k-PD<D)
__global__ void conv_B_kernel(const float* __restrict__ Win, unsigned short* __restrict__ Bt,
                              int D, int PD, int PK) {
    long idx = (long)blockIdx.x * blockDim.x + threadIdx.x;
    long total = (long)PD * (PK / 4);
    if (idx >= total) return;
    int n = (int)(idx / (PK / 4));
    int k4 = (int)(idx - (long)n * (PK / 4)) * 4;
    ushort4 o = make_ushort4(0, 0, 0, 0);
    unsigned short t[4] = {0, 0, 0, 0};
    if (n < D) {
#pragma unroll
        for (int q = 0; q < 4; ++q) {
            int k = k4 + q;
            int srcrow; bool valid;
            if (k < PD) { srcrow = k;            valid = (k < D); }
            else        { srcrow = D + (k - PD); valid = ((k - PD) < D); }
            if (valid) t[q] = f2bf(Win[(long)srcrow * D + n]);
        }
    }
    o.x = t[0]; o.y = t[1]; o.z = t[2]; o.w = t[3];
    *reinterpret_cast<ushort4*>(&Bt[(long)n * PK + k4]) = o;
}

__global__ void wpad_kernel(const float* __restrict__ w_out, float* __restrict__ wpad,
                            int D, int PD) {
    int n = blockIdx.x * blockDim.x + threadIdx.x;
    if (n < PD) wpad[n] = (n < D) ? w_out[n] : 0.f;
}

// bias_dot = b_pred_out + sum_c b_pred_in[c]*w_out[c]
__global__ void bias_dot_kernel(const float* __restrict__ b_in, const float* __restrict__ w_out,
                                const float* __restrict__ b_out, float* __restrict__ bias_dot, int D) {
    __shared__ float sm[256];
    float s = 0.f;
    for (int c = threadIdx.x; c < D; c += 256) s = fmaf(b_in[c], w_out[c], s);
    sm[threadIdx.x] = s;
    __syncthreads();
    for (int st = 128; st > 0; st >>= 1) {
        if (threadIdx.x < st) sm[threadIdx.x] += sm[threadIdx.x + st];
        __syncthreads();
    }
    if (threadIdx.x == 0) bias_dot[0] = sm[0] + b_out[0];
}

__global__ void initw_kernel(float* __restrict__ w, const float* __restrict__ bias_dot, int T) {
    int i = blockIdx.x * blockDim.x + threadIdx.x;
    if (i < T) w[i] = bias_dot[0];
}

// ---------------------------------------------------------------------------
// Fused pred GEMM, bf16 MFMA.
//   A row r = concat(emb16[trip[r][0]], emb16[trip[r][2]])  (PK = 2*PD)
//   C = A @ Bt^T, then weights[r] += sum_n C[r][n]*wpad[n]  (atomic partials).
// Tile BM=128 x BN=128 x BK=32, 256 threads (4 waves), each wave 64x64.
// Staging: global_load_lds width=16, XOR chunk swizzle (slot = c ^ ((row>>1)&3))
// to keep ds_read_b128 at free 2-way conflicts.
// ---------------------------------------------------------------------------
__global__ __launch_bounds__(256) void pred_gemm_bf16_kernel(
    const unsigned short* __restrict__ emb16, const int* __restrict__ trip,
    const unsigned short* __restrict__ Bt, const float* __restrict__ wpad,
    float* __restrict__ weights, int T, int PD, int PK) {

    __shared__ __align__(16) unsigned short As[128 * 32];  // 8 KB, row-major [128][32]
    __shared__ __align__(16) unsigned short Bs[128 * 32];  // 8 KB, [n_local][32]
    __shared__ int ls[128];
    __shared__ int lo[128];

    const int tid  = threadIdx.x;
    const int w    = tid >> 6;
    const int lane = tid & 63;
    const int row0 = blockIdx.x * 128;
    const int col0 = blockIdx.y * 128;

    if (tid < 128) {
        int r = row0 + tid;
        int a = 0, b = 0;
        if (r < T) { a = trip[(long)r * 3 + 0]; b = trip[(long)r * 3 + 2]; }
        ls[tid] = a; lo[tid] = b;
    }
    __syncthreads();

    // ---- staging assignment: wave w owns A chunks {2w,2w+1} and B chunks {2w,2w+1}
    const int r0   = 2 * w * 16 + (lane >> 2);       // row for chunk 2w
    const int r1   = (2 * w + 1) * 16 + (lane >> 2); // row for chunk 2w+1
    const int slot = lane & 3;
    const int c0   = slot ^ ((r0 >> 1) & 3);         // swizzled source chunk
    const int c1   = slot ^ ((r1 >> 1) & 3);

    const int sA0 = ls[r0], oA0 = lo[r0];
    const int sA1 = ls[r1], oA1 = lo[r1];

    const unsigned short* pA0s = emb16 + (long)sA0 * PD + c0 * 8;
    const unsigned short* pA0o = emb16 + (long)oA0 * PD + c0 * 8;
    const unsigned short* pA1s = emb16 + (long)sA1 * PD + c1 * 8;
    const unsigned short* pA1o = emb16 + (long)oA1 * PD + c1 * 8;
    const unsigned short* pB0  = Bt + (long)(col0 + r0) * PK + c0 * 8;
    const unsigned short* pB1  = Bt + (long)(col0 + r1) * PK + c1 * 8;

    unsigned short* dA0 = As + 2 * w * 512;        // 1KB chunks (512 shorts)
    unsigned short* dA1 = As + (2 * w + 1) * 512;
    unsigned short* dB0 = Bs + 2 * w * 512;
    unsigned short* dB1 = Bs + (2 * w + 1) * 512;

    // ---- compute-side LDS fragment pointers (k0-independent)
    const int wrow = (w & 1) * 64;
    const int wcol = (w >> 1) * 64;
    const int lm = lane & 15, q = lane >> 4;
    const s16x8* pa[4];
    const s16x8* pb[4];
#pragma unroll
    for (int i = 0; i < 4; ++i) {
        int r = wrow + i * 16 + lm;
        int cs = q ^ ((r >> 1) & 3);
        pa[i] = reinterpret_cast<const s16x8*>(As + r * 32 + cs * 8);
        int n = wcol + i * 16 + lm;
        int cs2 = q ^ ((n >> 1) & 3);
        pb[i] = reinterpret_cast<const s16x8*>(Bs + n * 32 + cs2 * 8);
    }

    f32x4 acc[4][4];
#pragma unroll
    for (int i = 0; i < 4; ++i)
#pragma unroll
        for (int j = 0; j < 4; ++j) acc[i][j] = (f32x4)0.f;

    for (int k0 = 0; k0 < PK; k0 += 32) {
        const int kh = k0 & (PD - 1);
        const unsigned short* ga0 = ((k0 < PD) ? pA0s : pA0o) + kh;
        const unsigned short* ga1 = ((k0 < PD) ? pA1s : pA1o) + kh;
        async_ld16(ga0, dA0);
        async_ld16(ga1, dA1);
        async_ld16(pB0 + k0, dB0);
        async_ld16(pB1 + k0, dB1);
        __syncthreads();   // drains vmcnt (compiler) -> LDS tile complete

        s16x8 af[4], bf[4];
#pragma unroll
        for (int i = 0; i < 4; ++i) { af[i] = *pa[i]; bf[i] = *pb[i]; }
#pragma unroll
        for (int i = 0; i < 4; ++i)
#pragma unroll
            for (int j = 0; j < 4; ++j)
                acc[i][j] = __builtin_amdgcn_mfma_f32_16x16x32_bf16(af[i], bf[j], acc[i][j], 0, 0, 0);
        __syncthreads();   // all reads done before next stage overwrites
    }

    // ---- epilogue: weights[row] += sum_n C[row][n] * wpad[n]
    float wv[4];
#pragma unroll
    for (int j = 0; j < 4; ++j) wv[j] = wpad[col0 + wcol + j * 16 + lm];

#pragma unroll
    for (int i = 0; i < 4; ++i) {
        float pr[4];
#pragma unroll
        for (int reg = 0; reg < 4; ++reg)
            pr[reg] = acc[i][0][reg] * wv[0] + acc[i][1][reg] * wv[1] +
                      acc[i][2][reg] * wv[2] + acc[i][3][reg] * wv[3];
#pragma unroll
        for (int mask = 1; mask < 16; mask <<= 1)
#pragma unroll
            for (int reg = 0; reg < 4; ++reg)
                pr[reg] += __shfl_xor(pr[reg], mask);
        if (lm == 0) {
#pragma unroll
            for (int reg = 0; reg < 4; ++reg) {
                int row = row0 + wrow + i * 16 + q * 4 + reg;
                if (row < T) atomicAdd(&weights[row], pr[reg]);
            }
        }
    }
}

// ---------------------------------------------------------------------------

extern "C" void kernel_launch(void* const* d_in, const int* in_sizes, int n_in,
                              void* d_out, int out_size, void* d_ws, size_t ws_size,
                              hipStream_t stream) {
    const float* feats      = (const float*)d_in[0];
    const float* W_aff      = (const float*)d_in[1];
    const float* b_aff      = (const float*)d_in[2];
    const float* W_gcn      = (const float*)d_in[3];
    const float* b_gcn      = (const float*)d_in[4];
    const float* W_pred_in  = (const float*)d_in[5];
    const float* b_pred_in  = (const float*)d_in[6];
    const float* W_pred_out = (const float*)d_in[7];
    const float* b_pred_out = (const float*)d_in[8];
    const int*   src        = (const int*)d_in[9];
    const int*   dst        = (const int*)d_in[10];
    const int*   trip       = (const int*)d_in[11];

    const int D = in_sizes[2];           // 500
    const int F = in_sizes[1] / D;       // 128
    const int N = in_sizes[0] / F;       // 50000
    const int E = in_sizes[9];           // 800000
    const int T = in_sizes[11] / 3;      // 200000

    const int PD = (D + 31) & ~31;       // 512
    const int PK = 2 * PD;               // 1024

    float* weights = (float*)d_out;          // [T]
    float* emb     = (float*)d_out + T;      // [N*D]

    // workspace layout (floats); emb16 aliases xw (xw dead after scatter)
    float*          xw    = (float*)d_ws;                 // N*D fp32
    unsigned short* emb16 = (unsigned short*)d_ws;        // N*PD bf16 (alias)
    float*    Wc   = xw + (size_t)N * D;                  // F*D
    float*    bc   = Wc + (size_t)F * D;                  // D
    float*    ns   = bc + D;                              // N
    float*    nd   = ns + N;                              // N
    unsigned* outd = (unsigned*)(nd + N);                 // N
    unsigned* ind  = outd + N;                            // N
    unsigned short* Bt = (unsigned short*)(ind + N);      // PD*PK bf16
    float*    wpad = (float*)(Bt + (size_t)PD * PK);      // PD
    float*    bdot = wpad + PD;                           // 1

    hipMemsetAsync(outd, 0, 2 * (size_t)N * sizeof(unsigned), stream);
    hipMemsetAsync(emb, 0, (size_t)N * D * sizeof(float), stream);

    // degrees + norms
    degree_kernel<<<(E + 255) / 256, 256, 0, stream>>>(src, dst, outd, ind, E);
    norm_kernel<<<(N + 255) / 256, 256, 0, stream>>>(outd, ind, ns, nd, N);

    // pred-weight preprocessing (independent of graph part)
    conv_B_kernel<<<(int)(((long)PD * (PK / 4) + 255) / 256), 256, 0, stream>>>(W_pred_in, Bt, D, PD, PK);
    wpad_kernel<<<(PD + 255) / 256, 256, 0, stream>>>(W_pred_out, wpad, D, PD);
    bias_dot_kernel<<<1, 256, 0, stream>>>(b_pred_in, W_pred_out, b_pred_out, bdot, D);
    initw_kernel<<<(T + 255) / 256, 256, 0, stream>>>(weights, bdot, T);

    // Wc = W_aff @ W_gcn ; bc = b_aff @ W_gcn
    {
        dim3 grid((F + 63) / 64, (D + 63) / 64);
        sgemm_kernel<false><<<grid, 256, 0, stream>>>(W_aff, D, W_gcn, D, nullptr,
                                                      Wc, D, F, D, D);
    }
    bcomb_kernel<<<(D + 255) / 256, 256, 0, stream>>>(b_aff, W_gcn, bc, D);

    // xw = feats @ Wc + bc
    {
        dim3 grid((N + 63) / 64, (D + 63) / 64);
        sgemm_kernel<true><<<grid, 256, 0, stream>>>(feats, F, Wc, D, bc,
                                                     xw, D, N, D, F);
    }

    // scatter messages (edges + self loops) into emb, then normalize + bias
    scatter_kernel<<<E + N, 128, 0, stream>>>(xw, src, dst, ns, emb, E, D);
    {
        long total4 = (long)N * D / 4;
        finalize_kernel<<<(unsigned)((total4 + 255) / 256), 256, 0, stream>>>(emb, nd, b_gcn, N, D);
    }

    // emb -> bf16 padded (aliases xw; xw is dead after scatter)
    {
        long tot = (long)N * (PD / 4);
        conv_emb_kernel<<<(unsigned)((tot + 255) / 256), 256, 0, stream>>>(emb, emb16, N, D, PD);
    }

    // fused pred GEMM (bf16 MFMA)
    {
        dim3 grid((T + 127) / 128, PD / 128);
        pred_gemm_bf16_kernel<<<grid, 256, 0, stream>>>(emb16, trip, Bt, wpad, weights, T, PD, PK);
    }
}

// Round 3
// 1262.464 us; speedup vs baseline: 3.9485x; 1.9286x over previous
//
#include <hip/hip_runtime.h>

// ---------------------------------------------------------------------------
// Encoder: xw = (feats@(W_aff@W_gcn) + b_aff@W_gcn) * ns[row]  (msg pre-scaled)
// GCN aggregate via CSR gather (pull) + self loop, fused *nd + b_gcn -> emb
// pred: weights = ([emb[s],emb[o]] @ W_pred_in + b_in) @ w_out + b_out
//   bf16 MFMA GEMM (K,N padded 1024/512), final dot fused, bias folded.
// ---------------------------------------------------------------------------

typedef float f32x4 __attribute__((ext_vector_type(4)));
typedef short s16x8 __attribute__((ext_vector_type(8)));

__device__ __forceinline__ unsigned short f2bf(float f) {
    unsigned u = __float_as_uint(f);
    unsigned r = (u + 0x7FFFu + ((u >> 16) & 1u)) >> 16;
    return (unsigned short)r;
}

__device__ __forceinline__ void async_ld16(const void* g, void* lds) {
    __builtin_amdgcn_global_load_lds(
        (const __attribute__((address_space(1))) unsigned int*)g,
        (__attribute__((address_space(3))) unsigned int*)lds,
        16, 0, 0);
}

// ---------------------------------------------------------------------------
__global__ void degree_kernel(const int* __restrict__ src, const int* __restrict__ dst,
                              unsigned* __restrict__ outd, unsigned* __restrict__ ind, int E) {
    int e = blockIdx.x * blockDim.x + threadIdx.x;
    if (e < E) {
        atomicAdd(&outd[src[e]], 1u);
        atomicAdd(&ind[dst[e]], 1u);
    }
}

__global__ void norm_kernel(const unsigned* __restrict__ outd, const unsigned* __restrict__ ind,
                            float* __restrict__ ns, float* __restrict__ nd, int N) {
    int i = blockIdx.x * blockDim.x + threadIdx.x;
    if (i < N) {
        ns[i] = rsqrtf((float)(outd[i] + 1u));   // +1 self loop; always > 0
        nd[i] = rsqrtf((float)(ind[i] + 1u));
    }
}

// Exclusive prefix scan of ind[0..N) -> row_ptr[0..N], plus cursor copy.
// Single block, 1024 threads, sequential chunks per thread.
__global__ __launch_bounds__(1024) void scan_kernel(const unsigned* __restrict__ ind,
                                                    int* __restrict__ row_ptr,
                                                    int* __restrict__ cursor, int N) {
    __shared__ int part[1024];
    const int tid = threadIdx.x;
    const int CH = (N + 1023) >> 10;
    const int base = tid * CH;
    int s = 0;
    for (int i = 0; i < CH; ++i) {
        int idx = base + i;
        if (idx < N) s += (int)ind[idx];
    }
    part[tid] = s;
    __syncthreads();
    for (int st = 1; st < 1024; st <<= 1) {
        int v = (tid >= st) ? part[tid - st] : 0;
        __syncthreads();
        part[tid] += v;
        __syncthreads();
    }
    int run = (tid == 0) ? 0 : part[tid - 1];
    for (int i = 0; i < CH; ++i) {
        int idx = base + i;
        if (idx < N) {
            row_ptr[idx] = run;
            cursor[idx]  = run;
            run += (int)ind[idx];
        }
    }
    if (tid == 1023) row_ptr[N] = part[1023];
}

__global__ void csr_fill_kernel(const int* __restrict__ src, const int* __restrict__ dst,
                                int* __restrict__ cursor, int* __restrict__ csr_src, int E) {
    int e = blockIdx.x * blockDim.x + threadIdx.x;
    if (e < E) {
        int pos = atomicAdd(&cursor[dst[e]], 1);
        csr_src[pos] = src[e];
    }
}

// bc[n] = sum_k b_aff[k] * W_gcn[k*D + n]
__global__ void bcomb_kernel(const float* __restrict__ b_aff, const float* __restrict__ W_gcn,
                             float* __restrict__ bc, int D) {
    int n = blockIdx.x * blockDim.x + threadIdx.x;
    if (n < D) {
        float s = 0.f;
        for (int k = 0; k < D; ++k) s = fmaf(b_aff[k], W_gcn[k * D + n], s);
        bc[n] = s;
    }
}

// ---------------------------------------------------------------------------
// Generic fp32 tiled GEMM; optional bias[col] and rowscale[row] in epilogue:
//   C = (A@B + bias) * rowscale
// ---------------------------------------------------------------------------
template <bool HAS_BIAS, bool HAS_SCALE>
__global__ __launch_bounds__(256) void sgemm_kernel(const float* __restrict__ A, int lda,
                                                    const float* __restrict__ B, int ldb,
                                                    const float* __restrict__ bias,
                                                    const float* __restrict__ rowscale,
                                                    float* __restrict__ C, int ldc,
                                                    int M, int N, int K) {
    __shared__ __align__(16) float As[16][68];
    __shared__ __align__(16) float Bs[16][68];
    const int tid = threadIdx.x;
    const int tx = tid & 15, ty = tid >> 4;
    const int row0 = blockIdx.x * 64;
    const int col0 = blockIdx.y * 64;

    const int a_row = tid >> 2;
    const int a_k   = (tid & 3) * 4;
    const int b_k   = tid >> 4;
    const int b_c   = (tid & 15) * 4;

    float acc[4][4] = {};

    for (int k0 = 0; k0 < K; k0 += 16) {
        float4 av = make_float4(0.f, 0.f, 0.f, 0.f);
        {
            int gr = row0 + a_row;
            int gk = k0 + a_k;
            if (gr < M) {
                if (gk + 3 < K) {
                    av = *reinterpret_cast<const float4*>(&A[(long)gr * lda + gk]);
                } else {
                    float t0 = (gk + 0 < K) ? A[(long)gr * lda + gk + 0] : 0.f;
                    float t1 = (gk + 1 < K) ? A[(long)gr * lda + gk + 1] : 0.f;
                    float t2 = (gk + 2 < K) ? A[(long)gr * lda + gk + 2] : 0.f;
                    float t3 = (gk + 3 < K) ? A[(long)gr * lda + gk + 3] : 0.f;
                    av = make_float4(t0, t1, t2, t3);
                }
            }
        }
        float4 bv = make_float4(0.f, 0.f, 0.f, 0.f);
        {
            int gk = k0 + b_k;
            int gc = col0 + b_c;
            if (gk < K) {
                if (gc + 3 < N) {
                    bv = *reinterpret_cast<const float4*>(&B[(long)gk * ldb + gc]);
                } else {
                    float t0 = (gc + 0 < N) ? B[(long)gk * ldb + gc + 0] : 0.f;
                    float t1 = (gc + 1 < N) ? B[(long)gk * ldb + gc + 1] : 0.f;
                    float t2 = (gc + 2 < N) ? B[(long)gk * ldb + gc + 2] : 0.f;
                    float t3 = (gc + 3 < N) ? B[(long)gk * ldb + gc + 3] : 0.f;
                    bv = make_float4(t0, t1, t2, t3);
                }
            }
        }
        __syncthreads();
        As[a_k + 0][a_row] = av.x;
        As[a_k + 1][a_row] = av.y;
        As[a_k + 2][a_row] = av.z;
        As[a_k + 3][a_row] = av.w;
        *reinterpret_cast<float4*>(&Bs[b_k][b_c]) = bv;
        __syncthreads();

#pragma unroll
        for (int k = 0; k < 16; ++k) {
            const float4 a = *reinterpret_cast<const float4*>(&As[k][ty * 4]);
            const float4 b = *reinterpret_cast<const float4*>(&Bs[k][tx * 4]);
            const float avv[4] = {a.x, a.y, a.z, a.w};
            const float bvv[4] = {b.x, b.y, b.z, b.w};
#pragma unroll
            for (int i = 0; i < 4; ++i)
#pragma unroll
                for (int j = 0; j < 4; ++j)
                    acc[i][j] = fmaf(avv[i], bvv[j], acc[i][j]);
        }
    }

#pragma unroll
    for (int i = 0; i < 4; ++i) {
        int r = row0 + ty * 4 + i;
        if (r >= M) continue;
        float sc = HAS_SCALE ? rowscale[r] : 1.f;
#pragma unroll
        for (int j = 0; j < 4; ++j) {
            int c = col0 + tx * 4 + j;
            if (c < N) {
                float v = acc[i][j];
                if (HAS_BIAS) v += bias[c];
                if (HAS_SCALE) v *= sc;
                C[(long)r * ldc + c] = v;
            }
        }
    }
}

// ---------------------------------------------------------------------------
// CSR gather: emb[d] = (sum_{s in in(d)} xws[s] + xws[d]) * nd[d] + b_gcn
// (xws rows pre-scaled by ns[src]). One 128-thread block per node; neighbor
// ids staged in LDS chunks; each thread owns one float4 column slab.
// ---------------------------------------------------------------------------
__global__ __launch_bounds__(128) void gather_kernel(
    const float* __restrict__ xws, const int* __restrict__ csr_src,
    const int* __restrict__ row_ptr, const float* __restrict__ nd,
    const float* __restrict__ b_gcn, float* __restrict__ emb, int D) {
    __shared__ int sn[128];
    const int d = blockIdx.x;
    const int tid = threadIdx.x;
    const int beg = row_ptr[d], end = row_ptr[d + 1];
    const int c4 = tid * 4;
    const bool act = c4 < D;

    float4 acc = make_float4(0.f, 0.f, 0.f, 0.f);
    if (act) acc = *reinterpret_cast<const float4*>(&xws[(long)d * D + c4]);  // self loop

    for (int j0 = beg; j0 < end; j0 += 128) {
        int cnt = min(128, end - j0);
        __syncthreads();
        if (tid < cnt) sn[tid] = csr_src[j0 + tid];
        __syncthreads();
        for (int k = 0; k < cnt; ++k) {
            if (act) {
                const float4 v = *reinterpret_cast<const float4*>(&xws[(long)sn[k] * D + c4]);
                acc.x += v.x; acc.y += v.y; acc.z += v.z; acc.w += v.w;
            }
        }
    }

    if (act) {
        float s = nd[d];
        float4 bg = *reinterpret_cast<const float4*>(&b_gcn[c4]);
        float4 o;
        o.x = fmaf(acc.x, s, bg.x);
        o.y = fmaf(acc.y, s, bg.y);
        o.z = fmaf(acc.z, s, bg.z);
        o.w = fmaf(acc.w, s, bg.w);
        *reinterpret_cast<float4*>(&emb[(long)d * D + c4]) = o;
    }
}

// ---------------------------------------------------------------------------
// bf16 conversion / padding kernels
// ---------------------------------------------------------------------------
__global__ void conv_emb_kernel(const float* __restrict__ emb, unsigned short* __restrict__ emb16,
                                int N, int D, int PD) {
    long idx = (long)blockIdx.x * blockDim.x + threadIdx.x;
    long total = (long)N * (PD / 4);
    if (idx >= total) return;
    int node = (int)(idx / (PD / 4));
    int c4 = (int)(idx - (long)node * (PD / 4)) * 4;
    ushort4 o = make_ushort4(0, 0, 0, 0);
    if (c4 + 3 < D) {
        float4 v = *reinterpret_cast<const float4*>(&emb[(long)node * D + c4]);
        o.x = f2bf(v.x); o.y = f2bf(v.y); o.z = f2bf(v.z); o.w = f2bf(v.w);
    } else if (c4 < D) {
        const float* p = &emb[(long)node * D + c4];
        unsigned short t[4] = {0, 0, 0, 0};
        for (int k = 0; k < 4; ++k) if (c4 + k < D) t[k] = f2bf(p[k]);
        o.x = t[0]; o.y = t[1]; o.z = t[2]; o.w = t[3];
    }
    *reinterpret_cast<ushort4*>(&emb16[(long)node * PD + c4]) = o;
}

// W_pred_in [2D][D] -> Bt bf16 [PD][PK] (transposed + split-pad per concat half)
__global__ void conv_B_kernel(const float* __restrict__ Win, unsigned short* __restrict__ Bt,
                              int D, int PD, int PK) {
    long idx = (long)blockIdx.x * blockDim.x + threadIdx.x;
    long total = (long)PD * (PK / 4);
    if (idx >= total) return;
    int n = (int)(idx / (PK / 4));
    int k4 = (int)(idx - (long)n * (PK / 4)) * 4;
    ushort4 o = make_ushort4(0, 0, 0, 0);
    unsigned short t[4] = {0, 0, 0, 0};
    if (n < D) {
#pragma unroll
        for (int q = 0; q < 4; ++q) {
            int k = k4 + q;
            int srcrow; bool valid;
            if (k < PD) { srcrow = k;            valid = (k < D); }
            else        { srcrow = D + (k - PD); valid = ((k - PD) < D); }
            if (valid) t[q] = f2bf(Win[(long)srcrow * D + n]);
        }
    }
    o.x = t[0]; o.y = t[1]; o.z = t[2]; o.w = t[3];
    *reinterpret_cast<ushort4*>(&Bt[(long)n * PK + k4]) = o;
}

__global__ void wpad_kernel(const float* __restrict__ w_out, float* __restrict__ wpad,
                            int D, int PD) {
    int n = blockIdx.x * blockDim.x + threadIdx.x;
    if (n < PD) wpad[n] = (n < D) ? w_out[n] : 0.f;
}

__global__ void bias_dot_kernel(const float* __restrict__ b_in, const float* __restrict__ w_out,
                                const float* __restrict__ b_out, float* __restrict__ bias_dot, int D) {
    __shared__ float sm[256];
    float s = 0.f;
    for (int c = threadIdx.x; c < D; c += 256) s = fmaf(b_in[c], w_out[c], s);
    sm[threadIdx.x] = s;
    __syncthreads();
    for (int st = 128; st > 0; st >>= 1) {
        if (threadIdx.x < st) sm[threadIdx.x] += sm[threadIdx.x + st];
        __syncthreads();
    }
    if (threadIdx.x == 0) bias_dot[0] = sm[0] + b_out[0];
}

__global__ void initw_kernel(float* __restrict__ w, const float* __restrict__ bias_dot, int T) {
    int i = blockIdx.x * blockDim.x + threadIdx.x;
    if (i < T) w[i] = bias_dot[0];
}

// ---------------------------------------------------------------------------
// Fused pred GEMM, bf16 MFMA. (unchanged from round 2)
// ---------------------------------------------------------------------------
__global__ __launch_bounds__(256) void pred_gemm_bf16_kernel(
    const unsigned short* __restrict__ emb16, const int* __restrict__ trip,
    const unsigned short* __restrict__ Bt, const float* __restrict__ wpad,
    float* __restrict__ weights, int T, int PD, int PK) {

    __shared__ __align__(16) unsigned short As[128 * 32];
    __shared__ __align__(16) unsigned short Bs[128 * 32];
    __shared__ int ls[128];
    __shared__ int lo[128];

    const int tid  = threadIdx.x;
    const int w    = tid >> 6;
    const int lane = tid & 63;
    const int row0 = blockIdx.x * 128;
    const int col0 = blockIdx.y * 128;

    if (tid < 128) {
        int r = row0 + tid;
        int a = 0, b = 0;
        if (r < T) { a = trip[(long)r * 3 + 0]; b = trip[(long)r * 3 + 2]; }
        ls[tid] = a; lo[tid] = b;
    }
    __syncthreads();

    const int r0   = 2 * w * 16 + (lane >> 2);
    const int r1   = (2 * w + 1) * 16 + (lane >> 2);
    const int slot = lane & 3;
    const int c0   = slot ^ ((r0 >> 1) & 3);
    const int c1   = slot ^ ((r1 >> 1) & 3);

    const int sA0 = ls[r0], oA0 = lo[r0];
    const int sA1 = ls[r1], oA1 = lo[r1];

    const unsigned short* pA0s = emb16 + (long)sA0 * PD + c0 * 8;
    const unsigned short* pA0o = emb16 + (long)oA0 * PD + c0 * 8;
    const unsigned short* pA1s = emb16 + (long)sA1 * PD + c1 * 8;
    const unsigned short* pA1o = emb16 + (long)oA1 * PD + c1 * 8;
    const unsigned short* pB0  = Bt + (long)(col0 + r0) * PK + c0 * 8;
    const unsigned short* pB1  = Bt + (long)(col0 + r1) * PK + c1 * 8;

    unsigned short* dA0 = As + 2 * w * 512;
    unsigned short* dA1 = As + (2 * w + 1) * 512;
    unsigned short* dB0 = Bs + 2 * w * 512;
    unsigned short* dB1 = Bs + (2 * w + 1) * 512;

    const int wrow = (w & 1) * 64;
    const int wcol = (w >> 1) * 64;
    const int lm = lane & 15, q = lane >> 4;
    const s16x8* pa[4];
    const s16x8* pb[4];
#pragma unroll
    for (int i = 0; i < 4; ++i) {
        int r = wrow + i * 16 + lm;
        int cs = q ^ ((r >> 1) & 3);
        pa[i] = reinterpret_cast<const s16x8*>(As + r * 32 + cs * 8);
        int n = wcol + i * 16 + lm;
        int cs2 = q ^ ((n >> 1) & 3);
        pb[i] = reinterpret_cast<const s16x8*>(Bs + n * 32 + cs2 * 8);
    }

    f32x4 acc[4][4];
#pragma unroll
    for (int i = 0; i < 4; ++i)
#pragma unroll
        for (int j = 0; j < 4; ++j) acc[i][j] = (f32x4)0.f;

    for (int k0 = 0; k0 < PK; k0 += 32) {
        const int kh = k0 & (PD - 1);
        const unsigned short* ga0 = ((k0 < PD) ? pA0s : pA0o) + kh;
        const unsigned short* ga1 = ((k0 < PD) ? pA1s : pA1o) + kh;
        async_ld16(ga0, dA0);
        async_ld16(ga1, dA1);
        async_ld16(pB0 + k0, dB0);
        async_ld16(pB1 + k0, dB1);
        __syncthreads();

        s16x8 af[4], bf[4];
#pragma unroll
        for (int i = 0; i < 4; ++i) { af[i] = *pa[i]; bf[i] = *pb[i]; }
#pragma unroll
        for (int i = 0; i < 4; ++i)
#pragma unroll
            for (int j = 0; j < 4; ++j)
                acc[i][j] = __builtin_amdgcn_mfma_f32_16x16x32_bf16(af[i], bf[j], acc[i][j], 0, 0, 0);
        __syncthreads();
    }

    float wv[4];
#pragma unroll
    for (int j = 0; j < 4; ++j) wv[j] = wpad[col0 + wcol + j * 16 + lm];

#pragma unroll
    for (int i = 0; i < 4; ++i) {
        float pr[4];
#pragma unroll
        for (int reg = 0; reg < 4; ++reg)
            pr[reg] = acc[i][0][reg] * wv[0] + acc[i][1][reg] * wv[1] +
                      acc[i][2][reg] * wv[2] + acc[i][3][reg] * wv[3];
#pragma unroll
        for (int mask = 1; mask < 16; mask <<= 1)
#pragma unroll
            for (int reg = 0; reg < 4; ++reg)
                pr[reg] += __shfl_xor(pr[reg], mask);
        if (lm == 0) {
#pragma unroll
            for (int reg = 0; reg < 4; ++reg) {
                int row = row0 + wrow + i * 16 + q * 4 + reg;
                if (row < T) atomicAdd(&weights[row], pr[reg]);
            }
        }
    }
}

// ---------------------------------------------------------------------------

extern "C" void kernel_launch(void* const* d_in, const int* in_sizes, int n_in,
                              void* d_out, int out_size, void* d_ws, size_t ws_size,
                              hipStream_t stream) {
    const float* feats      = (const float*)d_in[0];
    const float* W_aff      = (const float*)d_in[1];
    const float* b_aff      = (const float*)d_in[2];
    const float* W_gcn      = (const float*)d_in[3];
    const float* b_gcn      = (const float*)d_in[4];
    const float* W_pred_in  = (const float*)d_in[5];
    const float* b_pred_in  = (const float*)d_in[6];
    const float* W_pred_out = (const float*)d_in[7];
    const float* b_pred_out = (const float*)d_in[8];
    const int*   src        = (const int*)d_in[9];
    const int*   dst        = (const int*)d_in[10];
    const int*   trip       = (const int*)d_in[11];

    const int D = in_sizes[2];           // 500
    const int F = in_sizes[1] / D;       // 128
    const int N = in_sizes[0] / F;       // 50000
    const int E = in_sizes[9];           // 800000
    const int T = in_sizes[11] / 3;      // 200000

    const int PD = (D + 31) & ~31;       // 512
    const int PK = 2 * PD;               // 1024

    float* weights = (float*)d_out;          // [T]
    float* emb     = (float*)d_out + T;      // [N*D]

    // workspace layout; emb16 aliases xw (xw dead after gather)
    float*          xw    = (float*)d_ws;                 // N*D fp32 (pre-scaled by ns)
    unsigned short* emb16 = (unsigned short*)d_ws;        // N*PD bf16 (alias)
    float*    Wc      = xw + (size_t)N * D;               // F*D
    float*    bc      = Wc + (size_t)F * D;               // D
    float*    ns      = bc + D;                           // N
    float*    nd      = ns + N;                           // N
    unsigned* outd    = (unsigned*)(nd + N);              // N
    unsigned* ind     = outd + N;                         // N
    unsigned short* Bt = (unsigned short*)(ind + N);      // PD*PK bf16
    float*    wpad    = (float*)(Bt + (size_t)PD * PK);   // PD
    float*    bdot    = wpad + PD;                        // 1
    int*      row_ptr = (int*)(bdot + 1);                 // N+1
    int*      cursor  = row_ptr + (N + 1);                // N
    int*      csr_src = cursor + N;                       // E

    hipMemsetAsync(outd, 0, 2 * (size_t)N * sizeof(unsigned), stream);

    // degrees + norms + CSR build
    degree_kernel<<<(E + 255) / 256, 256, 0, stream>>>(src, dst, outd, ind, E);
    norm_kernel<<<(N + 255) / 256, 256, 0, stream>>>(outd, ind, ns, nd, N);
    scan_kernel<<<1, 1024, 0, stream>>>(ind, row_ptr, cursor, N);
    csr_fill_kernel<<<(E + 255) / 256, 256, 0, stream>>>(src, dst, cursor, csr_src, E);

    // pred-weight preprocessing (independent of graph part)
    conv_B_kernel<<<(int)(((long)PD * (PK / 4) + 255) / 256), 256, 0, stream>>>(W_pred_in, Bt, D, PD, PK);
    wpad_kernel<<<(PD + 255) / 256, 256, 0, stream>>>(W_pred_out, wpad, D, PD);
    bias_dot_kernel<<<1, 256, 0, stream>>>(b_pred_in, W_pred_out, b_pred_out, bdot, D);
    initw_kernel<<<(T + 255) / 256, 256, 0, stream>>>(weights, bdot, T);

    // Wc = W_aff @ W_gcn ; bc = b_aff @ W_gcn
    {
        dim3 grid((F + 63) / 64, (D + 63) / 64);
        sgemm_kernel<false, false><<<grid, 256, 0, stream>>>(W_aff, D, W_gcn, D, nullptr,
                                                             nullptr, Wc, D, F, D, D);
    }
    bcomb_kernel<<<(D + 255) / 256, 256, 0, stream>>>(b_aff, W_gcn, bc, D);

    // xw = (feats @ Wc + bc) * ns[row]   (messages pre-scaled)
    {
        dim3 grid((N + 63) / 64, (D + 63) / 64);
        sgemm_kernel<true, true><<<grid, 256, 0, stream>>>(feats, F, Wc, D, bc,
                                                           ns, xw, D, N, D, F);
    }

    // CSR gather + self loop + finalize (emb written exactly once)
    gather_kernel<<<N, 128, 0, stream>>>(xw, csr_src, row_ptr, nd, b_gcn, emb, D);

    // emb -> bf16 padded (aliases xw; xw dead after gather)
    {
        long tot = (long)N * (PD / 4);
        conv_emb_kernel<<<(unsigned)((tot + 255) / 256), 256, 0, stream>>>(emb, emb16, N, D, PD);
    }

    // fused pred GEMM (bf16 MFMA)
    {
        dim3 grid((T + 127) / 128, PD / 128);
        pred_gemm_bf16_kernel<<<grid, 256, 0, stream>>>(emb16, trip, Bt, wpad, weights, T, PD, PK);
    }
}

// Round 4
// 892.707 us; speedup vs baseline: 5.5840x; 1.4142x over previous
//
#include <hip/hip_runtime.h>

// ---------------------------------------------------------------------------
// Encoder: xw = (feats@(W_aff@W_gcn) + b_aff@W_gcn) * ns[row]  (msg pre-scaled)
// GCN aggregate via CSR gather (pull) + self loop, fused *nd + b_gcn -> emb
// pred MLP is LINEAR => weights[r] = emb[s]·v1 + emb[o]·v2 + bias_dot with
//   v = W_pred_in @ W_pred_out  (u1/u2 per-node dots fused into gather).
// ---------------------------------------------------------------------------

// ---------------------------------------------------------------------------
__global__ void degree_kernel(const int* __restrict__ src, const int* __restrict__ dst,
                              unsigned* __restrict__ outd, unsigned* __restrict__ ind, int E) {
    int e = blockIdx.x * blockDim.x + threadIdx.x;
    if (e < E) {
        atomicAdd(&outd[src[e]], 1u);
        atomicAdd(&ind[dst[e]], 1u);
    }
}

__global__ void norm_kernel(const unsigned* __restrict__ outd, const unsigned* __restrict__ ind,
                            float* __restrict__ ns, float* __restrict__ nd, int N) {
    int i = blockIdx.x * blockDim.x + threadIdx.x;
    if (i < N) {
        ns[i] = rsqrtf((float)(outd[i] + 1u));   // +1 self loop; always > 0
        nd[i] = rsqrtf((float)(ind[i] + 1u));
    }
}

// Exclusive prefix scan of ind[0..N) -> row_ptr[0..N], plus cursor copy.
__global__ __launch_bounds__(1024) void scan_kernel(const unsigned* __restrict__ ind,
                                                    int* __restrict__ row_ptr,
                                                    int* __restrict__ cursor, int N) {
    __shared__ int part[1024];
    const int tid = threadIdx.x;
    const int CH = (N + 1023) >> 10;
    const int base = tid * CH;
    int s = 0;
    for (int i = 0; i < CH; ++i) {
        int idx = base + i;
        if (idx < N) s += (int)ind[idx];
    }
    part[tid] = s;
    __syncthreads();
    for (int st = 1; st < 1024; st <<= 1) {
        int v = (tid >= st) ? part[tid - st] : 0;
        __syncthreads();
        part[tid] += v;
        __syncthreads();
    }
    int run = (tid == 0) ? 0 : part[tid - 1];
    for (int i = 0; i < CH; ++i) {
        int idx = base + i;
        if (idx < N) {
            row_ptr[idx] = run;
            cursor[idx]  = run;
            run += (int)ind[idx];
        }
    }
    if (tid == 1023) row_ptr[N] = part[1023];
}

__global__ void csr_fill_kernel(const int* __restrict__ src, const int* __restrict__ dst,
                                int* __restrict__ cursor, int* __restrict__ csr_src, int E) {
    int e = blockIdx.x * blockDim.x + threadIdx.x;
    if (e < E) {
        int pos = atomicAdd(&cursor[dst[e]], 1);
        csr_src[pos] = src[e];
    }
}

// bc[n] = sum_k b_aff[k] * W_gcn[k*D + n]
__global__ void bcomb_kernel(const float* __restrict__ b_aff, const float* __restrict__ W_gcn,
                             float* __restrict__ bc, int D) {
    int n = blockIdx.x * blockDim.x + threadIdx.x;
    if (n < D) {
        float s = 0.f;
        for (int k = 0; k < D; ++k) s = fmaf(b_aff[k], W_gcn[k * D + n], s);
        bc[n] = s;
    }
}

// v[k] = sum_c W_pred_in[k*D + c] * w_out[c]   (one wave per row k, k < 2D)
__global__ void vcomb_kernel(const float* __restrict__ Win, const float* __restrict__ wout,
                             float* __restrict__ v, int D, int K2) {
    int k = blockIdx.x * (blockDim.x >> 6) + (threadIdx.x >> 6);
    int lane = threadIdx.x & 63;
    if (k >= K2) return;
    float s = 0.f;
    for (int c = lane; c < D; c += 64) s = fmaf(Win[(long)k * D + c], wout[c], s);
#pragma unroll
    for (int m = 32; m > 0; m >>= 1) s += __shfl_down(s, m);
    if (lane == 0) v[k] = s;
}

// bias_dot = b_pred_out + sum_c b_pred_in[c]*w_out[c]
__global__ void bias_dot_kernel(const float* __restrict__ b_in, const float* __restrict__ w_out,
                                const float* __restrict__ b_out, float* __restrict__ bias_dot, int D) {
    __shared__ float sm[256];
    float s = 0.f;
    for (int c = threadIdx.x; c < D; c += 256) s = fmaf(b_in[c], w_out[c], s);
    sm[threadIdx.x] = s;
    __syncthreads();
    for (int st = 128; st > 0; st >>= 1) {
        if (threadIdx.x < st) sm[threadIdx.x] += sm[threadIdx.x + st];
        __syncthreads();
    }
    if (threadIdx.x == 0) bias_dot[0] = sm[0] + b_out[0];
}

// ---------------------------------------------------------------------------
// Generic fp32 tiled GEMM; optional bias[col] and rowscale[row] in epilogue:
//   C = (A@B + bias) * rowscale
// ---------------------------------------------------------------------------
template <bool HAS_BIAS, bool HAS_SCALE>
__global__ __launch_bounds__(256) void sgemm_kernel(const float* __restrict__ A, int lda,
                                                    const float* __restrict__ B, int ldb,
                                                    const float* __restrict__ bias,
                                                    const float* __restrict__ rowscale,
                                                    float* __restrict__ C, int ldc,
                                                    int M, int N, int K) {
    __shared__ __align__(16) float As[16][68];
    __shared__ __align__(16) float Bs[16][68];
    const int tid = threadIdx.x;
    const int tx = tid & 15, ty = tid >> 4;
    const int row0 = blockIdx.x * 64;
    const int col0 = blockIdx.y * 64;

    const int a_row = tid >> 2;
    const int a_k   = (tid & 3) * 4;
    const int b_k   = tid >> 4;
    const int b_c   = (tid & 15) * 4;

    float acc[4][4] = {};

    for (int k0 = 0; k0 < K; k0 += 16) {
        float4 av = make_float4(0.f, 0.f, 0.f, 0.f);
        {
            int gr = row0 + a_row;
            int gk = k0 + a_k;
            if (gr < M) {
                if (gk + 3 < K) {
                    av = *reinterpret_cast<const float4*>(&A[(long)gr * lda + gk]);
                } else {
                    float t0 = (gk + 0 < K) ? A[(long)gr * lda + gk + 0] : 0.f;
                    float t1 = (gk + 1 < K) ? A[(long)gr * lda + gk + 1] : 0.f;
                    float t2 = (gk + 2 < K) ? A[(long)gr * lda + gk + 2] : 0.f;
                    float t3 = (gk + 3 < K) ? A[(long)gr * lda + gk + 3] : 0.f;
                    av = make_float4(t0, t1, t2, t3);
                }
            }
        }
        float4 bv = make_float4(0.f, 0.f, 0.f, 0.f);
        {
            int gk = k0 + b_k;
            int gc = col0 + b_c;
            if (gk < K) {
                if (gc + 3 < N) {
                    bv = *reinterpret_cast<const float4*>(&B[(long)gk * ldb + gc]);
                } else {
                    float t0 = (gc + 0 < N) ? B[(long)gk * ldb + gc + 0] : 0.f;
                    float t1 = (gc + 1 < N) ? B[(long)gk * ldb + gc + 1] : 0.f;
                    float t2 = (gc + 2 < N) ? B[(long)gk * ldb + gc + 2] : 0.f;
                    float t3 = (gc + 3 < N) ? B[(long)gk * ldb + gc + 3] : 0.f;
                    bv = make_float4(t0, t1, t2, t3);
                }
            }
        }
        __syncthreads();
        As[a_k + 0][a_row] = av.x;
        As[a_k + 1][a_row] = av.y;
        As[a_k + 2][a_row] = av.z;
        As[a_k + 3][a_row] = av.w;
        *reinterpret_cast<float4*>(&Bs[b_k][b_c]) = bv;
        __syncthreads();

#pragma unroll
        for (int k = 0; k < 16; ++k) {
            const float4 a = *reinterpret_cast<const float4*>(&As[k][ty * 4]);
            const float4 b = *reinterpret_cast<const float4*>(&Bs[k][tx * 4]);
            const float avv[4] = {a.x, a.y, a.z, a.w};
            const float bvv[4] = {b.x, b.y, b.z, b.w};
#pragma unroll
            for (int i = 0; i < 4; ++i)
#pragma unroll
                for (int j = 0; j < 4; ++j)
                    acc[i][j] = fmaf(avv[i], bvv[j], acc[i][j]);
        }
    }

#pragma unroll
    for (int i = 0; i < 4; ++i) {
        int r = row0 + ty * 4 + i;
        if (r >= M) continue;
        float sc = HAS_SCALE ? rowscale[r] : 1.f;
#pragma unroll
        for (int j = 0; j < 4; ++j) {
            int c = col0 + tx * 4 + j;
            if (c < N) {
                float v = acc[i][j];
                if (HAS_BIAS) v += bias[c];
                if (HAS_SCALE) v *= sc;
                C[(long)r * ldc + c] = v;
            }
        }
    }
}

// ---------------------------------------------------------------------------
// CSR gather: emb[d] = (sum_{s in in(d)} xws[s] + xws[d]) * nd[d] + b_gcn
// (xws rows pre-scaled by ns[src]). One 128-thread block per node.
// Fused epilogue: u1[d] = emb[d]·v1, u2[d] = emb[d]·v2 (block reduce).
// ---------------------------------------------------------------------------
__global__ __launch_bounds__(128) void gather_kernel(
    const float* __restrict__ xws, const int* __restrict__ csr_src,
    const int* __restrict__ row_ptr, const float* __restrict__ nd,
    const float* __restrict__ b_gcn, const float* __restrict__ v1,
    const float* __restrict__ v2, float* __restrict__ emb,
    float* __restrict__ u1, float* __restrict__ u2, int D) {
    __shared__ int sn[128];
    __shared__ float r1[128], r2[128];
    const int d = blockIdx.x;
    const int tid = threadIdx.x;
    const int beg = row_ptr[d], end = row_ptr[d + 1];
    const int c4 = tid * 4;
    const bool act = c4 < D;   // D % 4 == 0

    float4 acc = make_float4(0.f, 0.f, 0.f, 0.f);
    if (act) acc = *reinterpret_cast<const float4*>(&xws[(long)d * D + c4]);  // self loop

    for (int j0 = beg; j0 < end; j0 += 128) {
        int cnt = min(128, end - j0);
        __syncthreads();
        if (tid < cnt) sn[tid] = csr_src[j0 + tid];
        __syncthreads();
        for (int k = 0; k < cnt; ++k) {
            if (act) {
                const float4 v = *reinterpret_cast<const float4*>(&xws[(long)sn[k] * D + c4]);
                acc.x += v.x; acc.y += v.y; acc.z += v.z; acc.w += v.w;
            }
        }
    }

    float p1 = 0.f, p2 = 0.f;
    if (act) {
        float s = nd[d];
        float4 bg = *reinterpret_cast<const float4*>(&b_gcn[c4]);
        float4 o;
        o.x = fmaf(acc.x, s, bg.x);
        o.y = fmaf(acc.y, s, bg.y);
        o.z = fmaf(acc.z, s, bg.z);
        o.w = fmaf(acc.w, s, bg.w);
        *reinterpret_cast<float4*>(&emb[(long)d * D + c4]) = o;
        float4 a1 = *reinterpret_cast<const float4*>(&v1[c4]);
        float4 a2 = *reinterpret_cast<const float4*>(&v2[c4]);
        p1 = o.x * a1.x + o.y * a1.y + o.z * a1.z + o.w * a1.w;
        p2 = o.x * a2.x + o.y * a2.y + o.z * a2.z + o.w * a2.w;
    }
    r1[tid] = p1;
    r2[tid] = p2;
    __syncthreads();
    for (int st = 64; st > 0; st >>= 1) {
        if (tid < st) { r1[tid] += r1[tid + st]; r2[tid] += r2[tid + st]; }
        __syncthreads();
    }
    if (tid == 0) { u1[d] = r1[0]; u2[d] = r2[0]; }
}

// weights[r] = u1[trip[r,0]] + u2[trip[r,2]] + bias_dot
__global__ void weights_kernel(const int* __restrict__ trip, const float* __restrict__ u1,
                               const float* __restrict__ u2, const float* __restrict__ bdot,
                               float* __restrict__ w, int T) {
    int r = blockIdx.x * blockDim.x + threadIdx.x;
    if (r < T) {
        int s = trip[(long)r * 3 + 0];
        int o = trip[(long)r * 3 + 2];
        w[r] = u1[s] + u2[o] + bdot[0];
    }
}

// ---------------------------------------------------------------------------

extern "C" void kernel_launch(void* const* d_in, const int* in_sizes, int n_in,
                              void* d_out, int out_size, void* d_ws, size_t ws_size,
                              hipStream_t stream) {
    const float* feats      = (const float*)d_in[0];
    const float* W_aff      = (const float*)d_in[1];
    const float* b_aff      = (const float*)d_in[2];
    const float* W_gcn      = (const float*)d_in[3];
    const float* b_gcn      = (const float*)d_in[4];
    const float* W_pred_in  = (const float*)d_in[5];
    const float* b_pred_in  = (const float*)d_in[6];
    const float* W_pred_out = (const float*)d_in[7];
    const float* b_pred_out = (const float*)d_in[8];
    const int*   src        = (const int*)d_in[9];
    const int*   dst        = (const int*)d_in[10];
    const int*   trip       = (const int*)d_in[11];

    const int D = in_sizes[2];           // 500
    const int F = in_sizes[1] / D;       // 128
    const int N = in_sizes[0] / F;       // 50000
    const int E = in_sizes[9];           // 800000
    const int T = in_sizes[11] / 3;      // 200000

    float* weights = (float*)d_out;          // [T]
    float* emb     = (float*)d_out + T;      // [N*D]

    // workspace layout (floats)
    float*    xw      = (float*)d_ws;                     // N*D (pre-scaled by ns)
    float*    Wc      = xw + (size_t)N * D;               // F*D
    float*    bc      = Wc + (size_t)F * D;               // D
    float*    ns      = bc + D;                           // N
    float*    nd      = ns + N;                           // N
    float*    v       = nd + N;                           // 2*D  (v1 | v2)
    float*    bdot    = v + 2 * D;                        // 1
    float*    u1      = bdot + 1;                         // N
    float*    u2      = u1 + N;                           // N
    unsigned* outd    = (unsigned*)(u2 + N);              // N
    unsigned* ind     = outd + N;                         // N
    int*      row_ptr = (int*)(ind + N);                  // N+1
    int*      cursor  = row_ptr + (N + 1);                // N
    int*      csr_src = cursor + N;                       // E

    hipMemsetAsync(outd, 0, 2 * (size_t)N * sizeof(unsigned), stream);

    // degrees + norms + CSR build
    degree_kernel<<<(E + 255) / 256, 256, 0, stream>>>(src, dst, outd, ind, E);
    norm_kernel<<<(N + 255) / 256, 256, 0, stream>>>(outd, ind, ns, nd, N);
    scan_kernel<<<1, 1024, 0, stream>>>(ind, row_ptr, cursor, N);
    csr_fill_kernel<<<(E + 255) / 256, 256, 0, stream>>>(src, dst, cursor, csr_src, E);

    // pred linearization: v = W_pred_in @ W_pred_out ; bias_dot
    vcomb_kernel<<<(2 * D + 3) / 4, 256, 0, stream>>>(W_pred_in, W_pred_out, v, D, 2 * D);
    bias_dot_kernel<<<1, 256, 0, stream>>>(b_pred_in, W_pred_out, b_pred_out, bdot, D);

    // Wc = W_aff @ W_gcn ; bc = b_aff @ W_gcn
    {
        dim3 grid((F + 63) / 64, (D + 63) / 64);
        sgemm_kernel<false, false><<<grid, 256, 0, stream>>>(W_aff, D, W_gcn, D, nullptr,
                                                             nullptr, Wc, D, F, D, D);
    }
    bcomb_kernel<<<(D + 255) / 256, 256, 0, stream>>>(b_aff, W_gcn, bc, D);

    // xw = (feats @ Wc + bc) * ns[row]   (messages pre-scaled)
    {
        dim3 grid((N + 63) / 64, (D + 63) / 64);
        sgemm_kernel<true, true><<<grid, 256, 0, stream>>>(feats, F, Wc, D, bc,
                                                           ns, xw, D, N, D, F);
    }

    // CSR gather + self loop + finalize; fused u1/u2 dots
    gather_kernel<<<N, 128, 0, stream>>>(xw, csr_src, row_ptr, nd, b_gcn,
                                         v, v + D, emb, u1, u2, D);

    // weights from per-node scalars
    weights_kernel<<<(T + 255) / 256, 256, 0, stream>>>(trip, u1, u2, bdot, weights, T);
}

// Round 5
// 670.090 us; speedup vs baseline: 7.4391x; 1.3322x over previous
//
#include <hip/hip_runtime.h>

// ---------------------------------------------------------------------------
// Algebra: emb = nd ⊙ (Â (ns ⊙ (feats@Wc + bc))) + b_gcn
//        = nd ⊙ ( g@Wc + h·bcᵀ ) + b_gcn     with g = Â(ns⊙feats), h = Â ns
// (Â = adjacency-by-dst incl. self loops; Wc = W_aff@W_gcn, bc = b_aff@W_gcn)
// Gather is done in F=128 feature space (4x less traffic than D=500 space).
// pred MLP is linear => weights[r] = emb[s]·v1 + emb[o]·v2 + bias_dot,
// v = W_pred_in @ W_pred_out; u-dots fused into the MFMA GEMM epilogue.
// ---------------------------------------------------------------------------

typedef float f32x4 __attribute__((ext_vector_type(4)));
typedef short s16x8 __attribute__((ext_vector_type(8)));

__device__ __forceinline__ unsigned short f2bf(float f) {
    unsigned u = __float_as_uint(f);
    unsigned r = (u + 0x7FFFu + ((u >> 16) & 1u)) >> 16;
    return (unsigned short)r;
}

__device__ __forceinline__ void async_ld16(const void* g, void* lds) {
    __builtin_amdgcn_global_load_lds(
        (const __attribute__((address_space(1))) unsigned int*)g,
        (__attribute__((address_space(3))) unsigned int*)lds,
        16, 0, 0);
}

// ---------------------------------------------------------------------------
__global__ void degree_kernel(const int* __restrict__ src, const int* __restrict__ dst,
                              unsigned* __restrict__ outd, unsigned* __restrict__ ind, int E) {
    int e = blockIdx.x * blockDim.x + threadIdx.x;
    if (e < E) {
        atomicAdd(&outd[src[e]], 1u);
        atomicAdd(&ind[dst[e]], 1u);
    }
}

__global__ void norm_kernel(const unsigned* __restrict__ outd, const unsigned* __restrict__ ind,
                            float* __restrict__ ns, float* __restrict__ nd, int N) {
    int i = blockIdx.x * blockDim.x + threadIdx.x;
    if (i < N) {
        ns[i] = rsqrtf((float)(outd[i] + 1u));   // +1 self loop; always > 0
        nd[i] = rsqrtf((float)(ind[i] + 1u));
    }
}

// Exclusive prefix scan of ind[0..N) -> row_ptr[0..N], plus cursor copy.
__global__ __launch_bounds__(1024) void scan_kernel(const unsigned* __restrict__ ind,
                                                    int* __restrict__ row_ptr,
                                                    int* __restrict__ cursor, int N) {
    __shared__ int part[1024];
    const int tid = threadIdx.x;
    const int CH = (N + 1023) >> 10;
    const int base = tid * CH;
    int s = 0;
    for (int i = 0; i < CH; ++i) {
        int idx = base + i;
        if (idx < N) s += (int)ind[idx];
    }
    part[tid] = s;
    __syncthreads();
    for (int st = 1; st < 1024; st <<= 1) {
        int v = (tid >= st) ? part[tid - st] : 0;
        __syncthreads();
        part[tid] += v;
        __syncthreads();
    }
    int run = (tid == 0) ? 0 : part[tid - 1];
    for (int i = 0; i < CH; ++i) {
        int idx = base + i;
        if (idx < N) {
            row_ptr[idx] = run;
            cursor[idx]  = run;
            run += (int)ind[idx];
        }
    }
    if (tid == 1023) row_ptr[N] = part[1023];
}

__global__ void csr_fill_kernel(const int* __restrict__ src, const int* __restrict__ dst,
                                int* __restrict__ cursor, int* __restrict__ csr_src, int E) {
    int e = blockIdx.x * blockDim.x + threadIdx.x;
    if (e < E) {
        int pos = atomicAdd(&cursor[dst[e]], 1);
        csr_src[pos] = src[e];
    }
}

// bc[n] = sum_k b_aff[k] * W_gcn[k*D + n]
__global__ void bcomb_kernel(const float* __restrict__ b_aff, const float* __restrict__ W_gcn,
                             float* __restrict__ bc, int D) {
    int n = blockIdx.x * blockDim.x + threadIdx.x;
    if (n < D) {
        float s = 0.f;
        for (int k = 0; k < D; ++k) s = fmaf(b_aff[k], W_gcn[k * D + n], s);
        bc[n] = s;
    }
}

// v[k] = sum_c W_pred_in[k*D + c] * w_out[c]   (one wave per row k, k < 2D)
__global__ void vcomb_kernel(const float* __restrict__ Win, const float* __restrict__ wout,
                             float* __restrict__ v, int D, int K2) {
    int k = blockIdx.x * (blockDim.x >> 6) + (threadIdx.x >> 6);
    int lane = threadIdx.x & 63;
    if (k >= K2) return;
    float s = 0.f;
    for (int c = lane; c < D; c += 64) s = fmaf(Win[(long)k * D + c], wout[c], s);
#pragma unroll
    for (int m = 32; m > 0; m >>= 1) s += __shfl_down(s, m);
    if (lane == 0) v[k] = s;
}

// bias_dot = b_pred_out + sum_c b_pred_in[c]*w_out[c]
__global__ void bias_dot_kernel(const float* __restrict__ b_in, const float* __restrict__ w_out,
                                const float* __restrict__ b_out, float* __restrict__ bias_dot, int D) {
    __shared__ float sm[256];
    float s = 0.f;
    for (int c = threadIdx.x; c < D; c += 256) s = fmaf(b_in[c], w_out[c], s);
    sm[threadIdx.x] = s;
    __syncthreads();
    for (int st = 128; st > 0; st >>= 1) {
        if (threadIdx.x < st) sm[threadIdx.x] += sm[threadIdx.x + st];
        __syncthreads();
    }
    if (threadIdx.x == 0) bias_dot[0] = sm[0] + b_out[0];
}

// Zero-pad small vectors to PD=512: bcp, bgp, v1p, v2p
__global__ void pad_kernel(const float* __restrict__ bc, const float* __restrict__ b_gcn,
                           const float* __restrict__ v, float* __restrict__ bcp,
                           float* __restrict__ bgp, float* __restrict__ v1p,
                           float* __restrict__ v2p, int D, int PD) {
    int i = blockIdx.x * blockDim.x + threadIdx.x;
    if (i < PD) {
        bcp[i] = (i < D) ? bc[i] : 0.f;
        bgp[i] = (i < D) ? b_gcn[i] : 0.f;
        v1p[i] = (i < D) ? v[i] : 0.f;
        v2p[i] = (i < D) ? v[D + i] : 0.f;
    }
}

// ---------------------------------------------------------------------------
// fp32 tiled GEMM (only used for the tiny Wc = W_aff @ W_gcn)
// ---------------------------------------------------------------------------
__global__ __launch_bounds__(256) void sgemm_kernel(const float* __restrict__ A, int lda,
                                                    const float* __restrict__ B, int ldb,
                                                    float* __restrict__ C, int ldc,
                                                    int M, int N, int K) {
    __shared__ __align__(16) float As[16][68];
    __shared__ __align__(16) float Bs[16][68];
    const int tid = threadIdx.x;
    const int tx = tid & 15, ty = tid >> 4;
    const int row0 = blockIdx.x * 64;
    const int col0 = blockIdx.y * 64;

    const int a_row = tid >> 2;
    const int a_k   = (tid & 3) * 4;
    const int b_k   = tid >> 4;
    const int b_c   = (tid & 15) * 4;

    float acc[4][4] = {};

    for (int k0 = 0; k0 < K; k0 += 16) {
        float4 av = make_float4(0.f, 0.f, 0.f, 0.f);
        {
            int gr = row0 + a_row;
            int gk = k0 + a_k;
            if (gr < M) {
                if (gk + 3 < K) {
                    av = *reinterpret_cast<const float4*>(&A[(long)gr * lda + gk]);
                } else {
                    float t0 = (gk + 0 < K) ? A[(long)gr * lda + gk + 0] : 0.f;
                    float t1 = (gk + 1 < K) ? A[(long)gr * lda + gk + 1] : 0.f;
                    float t2 = (gk + 2 < K) ? A[(long)gr * lda + gk + 2] : 0.f;
                    float t3 = (gk + 3 < K) ? A[(long)gr * lda + gk + 3] : 0.f;
                    av = make_float4(t0, t1, t2, t3);
                }
            }
        }
        float4 bv = make_float4(0.f, 0.f, 0.f, 0.f);
        {
            int gk = k0 + b_k;
            int gc = col0 + b_c;
            if (gk < K) {
                if (gc + 3 < N) {
                    bv = *reinterpret_cast<const float4*>(&B[(long)gk * ldb + gc]);
                } else {
                    float t0 = (gc + 0 < N) ? B[(long)gk * ldb + gc + 0] : 0.f;
                    float t1 = (gc + 1 < N) ? B[(long)gk * ldb + gc + 1] : 0.f;
                    float t2 = (gc + 2 < N) ? B[(long)gk * ldb + gc + 2] : 0.f;
                    float t3 = (gc + 3 < N) ? B[(long)gk * ldb + gc + 3] : 0.f;
                    bv = make_float4(t0, t1, t2, t3);
                }
            }
        }
        __syncthreads();
        As[a_k + 0][a_row] = av.x;
        As[a_k + 1][a_row] = av.y;
        As[a_k + 2][a_row] = av.z;
        As[a_k + 3][a_row] = av.w;
        *reinterpret_cast<float4*>(&Bs[b_k][b_c]) = bv;
        __syncthreads();

#pragma unroll
        for (int k = 0; k < 16; ++k) {
            const float4 a = *reinterpret_cast<const float4*>(&As[k][ty * 4]);
            const float4 b = *reinterpret_cast<const float4*>(&Bs[k][tx * 4]);
            const float avv[4] = {a.x, a.y, a.z, a.w};
            const float bvv[4] = {b.x, b.y, b.z, b.w};
#pragma unroll
            for (int i = 0; i < 4; ++i)
#pragma unroll
                for (int j = 0; j < 4; ++j)
                    acc[i][j] = fmaf(avv[i], bvv[j], acc[i][j]);
        }
    }

#pragma unroll
    for (int i = 0; i < 4; ++i) {
        int r = row0 + ty * 4 + i;
        if (r >= M) continue;
#pragma unroll
        for (int j = 0; j < 4; ++j) {
            int c = col0 + tx * 4 + j;
            if (c < N) C[(long)r * ldc + c] = acc[i][j];
        }
    }
}

// fs16[s][c] = bf16(feats[s][c] * ns[s])   (F = 128)
__global__ void conv_feats_kernel(const float* __restrict__ feats, const float* __restrict__ ns,
                                  unsigned short* __restrict__ fs16, int N) {
    int idx = blockIdx.x * blockDim.x + threadIdx.x;
    if (idx >= N * 16) return;
    int node = idx >> 4;
    int c = (idx & 15) * 8;
    float s = ns[node];
    const float* p = feats + (long)node * 128 + c;
    float4 a = *reinterpret_cast<const float4*>(p);
    float4 b = *reinterpret_cast<const float4*>(p + 4);
    uint4 o;
    o.x = (unsigned)f2bf(a.x * s) | ((unsigned)f2bf(a.y * s) << 16);
    o.y = (unsigned)f2bf(a.z * s) | ((unsigned)f2bf(a.w * s) << 16);
    o.z = (unsigned)f2bf(b.x * s) | ((unsigned)f2bf(b.y * s) << 16);
    o.w = (unsigned)f2bf(b.z * s) | ((unsigned)f2bf(b.w * s) << 16);
    *reinterpret_cast<uint4*>(fs16 + (long)node * 128 + c) = o;
}

// Wc [128][D] fp32 -> Bt [PD=512 rows n][128 k] bf16 (transposed, pad rows zero)
__global__ void conv_Bt_kernel(const float* __restrict__ Wc, unsigned short* __restrict__ Bt,
                               int D, int PD) {
    int idx = blockIdx.x * blockDim.x + threadIdx.x;   // PD*16 threads
    if (idx >= PD * 16) return;
    int n = idx >> 4;
    int k8 = (idx & 15) * 8;
    uint4 o = make_uint4(0, 0, 0, 0);
    if (n < D) {
        unsigned short t[8];
#pragma unroll
        for (int q = 0; q < 8; ++q) t[q] = f2bf(Wc[(long)(k8 + q) * D + n]);
        o.x = (unsigned)t[0] | ((unsigned)t[1] << 16);
        o.y = (unsigned)t[2] | ((unsigned)t[3] << 16);
        o.z = (unsigned)t[4] | ((unsigned)t[5] << 16);
        o.w = (unsigned)t[6] | ((unsigned)t[7] << 16);
    }
    *reinterpret_cast<uint4*>(Bt + (long)n * 128 + k8) = o;
}

// ---------------------------------------------------------------------------
// Feature-space CSR gather, wave per node:
//   g16[d] = bf16( Σ_{s∈in(d)} fs16[s] + fs16[d] )   (fp32 accum)
//   h[d]   = Σ ns[s] + ns[d]
// Lane owns 2 cols (ushort2 load per neighbor); neighbor ids broadcast by shfl.
// ---------------------------------------------------------------------------
__global__ __launch_bounds__(256) void gather_feats_kernel(
    const unsigned short* __restrict__ fs16, const int* __restrict__ csr_src,
    const int* __restrict__ row_ptr, const float* __restrict__ ns,
    unsigned short* __restrict__ g16, float* __restrict__ h, int N) {
    int d = blockIdx.x * 4 + (threadIdx.x >> 6);
    int lane = threadIdx.x & 63;
    if (d >= N) return;

    // self loop init
    unsigned su = *reinterpret_cast<const unsigned*>(fs16 + (long)d * 128 + lane * 2);
    float a0 = __uint_as_float(su << 16);
    float a1 = __uint_as_float(su & 0xFFFF0000u);
    float hacc = 0.f;

    const int beg = row_ptr[d], end = row_ptr[d + 1];
    for (int j0 = beg; j0 < end; j0 += 64) {
        int cnt = end - j0;
        if (cnt > 64) cnt = 64;
        int s = (lane < cnt) ? csr_src[j0 + lane] : 0;
        if (lane < cnt) hacc += ns[s];
        for (int k = 0; k < cnt; ++k) {
            int sk = __shfl(s, k);
            unsigned v = *reinterpret_cast<const unsigned*>(fs16 + (long)sk * 128 + lane * 2);
            a0 += __uint_as_float(v << 16);
            a1 += __uint_as_float(v & 0xFFFF0000u);
        }
    }
#pragma unroll
    for (int m = 32; m > 0; m >>= 1) hacc += __shfl_xor(hacc, m);
    if (lane == 0) h[d] = hacc + ns[d];
    unsigned o = (unsigned)f2bf(a0) | ((unsigned)f2bf(a1) << 16);
    *reinterpret_cast<unsigned*>(g16 + (long)d * 128 + lane * 2) = o;
}

// ---------------------------------------------------------------------------
// MFMA GEMM: emb[r][c] = nd[r]*( (g16@Wc)[r][c] + h[r]*bcp[c] ) + bgp[c]
// fused epilogue dots: u1[r] += Σ_c emb·v1p, u2[r] += Σ_c emb·v2p (atomic per col-block)
// BM=128 BN=128, K=128 (4 k-steps of 32), 256 threads / 4 waves of 64x64.
// ---------------------------------------------------------------------------
__global__ __launch_bounds__(256) void gcn_gemm_kernel(
    const unsigned short* __restrict__ g16, const unsigned short* __restrict__ Bt,
    const float* __restrict__ h, const float* __restrict__ nd,
    const float* __restrict__ bcp, const float* __restrict__ bgp,
    const float* __restrict__ v1p, const float* __restrict__ v2p,
    float* __restrict__ emb, float* __restrict__ u1, float* __restrict__ u2,
    int M, int D) {

    __shared__ __align__(16) unsigned short As[128 * 32];
    __shared__ __align__(16) unsigned short Bs[128 * 32];

    const int tid  = threadIdx.x;
    const int w    = tid >> 6;
    const int lane = tid & 63;
    const int row0 = blockIdx.x * 128;
    const int col0 = blockIdx.y * 128;

    // staging: wave w owns chunks {2w, 2w+1} of both A and B (16 rows x 32 k each)
    const int r0   = 2 * w * 16 + (lane >> 2);
    const int r1   = (2 * w + 1) * 16 + (lane >> 2);
    const int slot = lane & 3;
    const int c0   = slot ^ ((r0 >> 1) & 3);
    const int c1   = slot ^ ((r1 >> 1) & 3);

    const unsigned short* pA0 = g16 + (long)(row0 + r0) * 128 + c0 * 8;
    const unsigned short* pA1 = g16 + (long)(row0 + r1) * 128 + c1 * 8;
    const unsigned short* pB0 = Bt + (long)(col0 + r0) * 128 + c0 * 8;
    const unsigned short* pB1 = Bt + (long)(col0 + r1) * 128 + c1 * 8;

    unsigned short* dA0 = As + 2 * w * 512;
    unsigned short* dA1 = As + (2 * w + 1) * 512;
    unsigned short* dB0 = Bs + 2 * w * 512;
    unsigned short* dB1 = Bs + (2 * w + 1) * 512;

    const int wrow = (w & 1) * 64;
    const int wcol = (w >> 1) * 64;
    const int lm = lane & 15, q = lane >> 4;
    const s16x8* pa[4];
    const s16x8* pb[4];
#pragma unroll
    for (int i = 0; i < 4; ++i) {
        int r = wrow + i * 16 + lm;
        int cs = q ^ ((r >> 1) & 3);
        pa[i] = reinterpret_cast<const s16x8*>(As + r * 32 + cs * 8);
        int n = wcol + i * 16 + lm;
        int cs2 = q ^ ((n >> 1) & 3);
        pb[i] = reinterpret_cast<const s16x8*>(Bs + n * 32 + cs2 * 8);
    }

    f32x4 acc[4][4];
#pragma unroll
    for (int i = 0; i < 4; ++i)
#pragma unroll
        for (int j = 0; j < 4; ++j) acc[i][j] = (f32x4)0.f;

    for (int k0 = 0; k0 < 128; k0 += 32) {
        async_ld16(pA0 + k0, dA0);
        async_ld16(pA1 + k0, dA1);
        async_ld16(pB0 + k0, dB0);
        async_ld16(pB1 + k0, dB1);
        __syncthreads();

        s16x8 af[4], bf[4];
#pragma unroll
        for (int i = 0; i < 4; ++i) { af[i] = *pa[i]; bf[i] = *pb[i]; }
#pragma unroll
        for (int i = 0; i < 4; ++i)
#pragma unroll
            for (int j = 0; j < 4; ++j)
                acc[i][j] = __builtin_amdgcn_mfma_f32_16x16x32_bf16(af[i], bf[j], acc[i][j], 0, 0, 0);
        __syncthreads();
    }

    // epilogue: finalize emb + fused u-dots
    float bcv[4], bgv[4], w1[4], w2[4];
    int colv[4];
#pragma unroll
    for (int j = 0; j < 4; ++j) {
        int c = col0 + wcol + j * 16 + lm;
        colv[j] = c;
        bcv[j] = bcp[c];
        bgv[j] = bgp[c];
        w1[j] = v1p[c];
        w2[j] = v2p[c];
    }

#pragma unroll
    for (int i = 0; i < 4; ++i) {
        float p1[4], p2[4];
#pragma unroll
        for (int reg = 0; reg < 4; ++reg) {
            int row = row0 + wrow + i * 16 + q * 4 + reg;
            float hb = h[row];
            float sc = nd[row];
            float s1 = 0.f, s2 = 0.f;
#pragma unroll
            for (int j = 0; j < 4; ++j) {
                float o = fmaf(sc, acc[i][j][reg] + hb * bcv[j], bgv[j]);
                if (row < M && colv[j] < D) emb[(long)row * D + colv[j]] = o;
                s1 = fmaf(o, w1[j], s1);
                s2 = fmaf(o, w2[j], s2);
            }
            p1[reg] = s1;
            p2[reg] = s2;
        }
#pragma unroll
        for (int mask = 1; mask < 16; mask <<= 1)
#pragma unroll
            for (int reg = 0; reg < 4; ++reg) {
                p1[reg] += __shfl_xor(p1[reg], mask);
                p2[reg] += __shfl_xor(p2[reg], mask);
            }
        if (lm == 0) {
#pragma unroll
            for (int reg = 0; reg < 4; ++reg) {
                int row = row0 + wrow + i * 16 + q * 4 + reg;
                if (row < M) {
                    atomicAdd(&u1[row], p1[reg]);
                    atomicAdd(&u2[row], p2[reg]);
                }
            }
        }
    }
}

// weights[r] = u1[trip[r,0]] + u2[trip[r,2]] + bias_dot
__global__ void weights_kernel(const int* __restrict__ trip, const float* __restrict__ u1,
                               const float* __restrict__ u2, const float* __restrict__ bdot,
                               float* __restrict__ w, int T) {
    int r = blockIdx.x * blockDim.x + threadIdx.x;
    if (r < T) {
        int s = trip[(long)r * 3 + 0];
        int o = trip[(long)r * 3 + 2];
        w[r] = u1[s] + u2[o] + bdot[0];
    }
}

// ---------------------------------------------------------------------------

extern "C" void kernel_launch(void* const* d_in, const int* in_sizes, int n_in,
                              void* d_out, int out_size, void* d_ws, size_t ws_size,
                              hipStream_t stream) {
    const float* feats      = (const float*)d_in[0];
    const float* W_aff      = (const float*)d_in[1];
    const float* b_aff      = (const float*)d_in[2];
    const float* W_gcn      = (const float*)d_in[3];
    const float* b_gcn      = (const float*)d_in[4];
    const float* W_pred_in  = (const float*)d_in[5];
    const float* b_pred_in  = (const float*)d_in[6];
    const float* W_pred_out = (const float*)d_in[7];
    const float* b_pred_out = (const float*)d_in[8];
    const int*   src        = (const int*)d_in[9];
    const int*   dst        = (const int*)d_in[10];
    const int*   trip       = (const int*)d_in[11];

    const int D = in_sizes[2];           // 500
    const int F = in_sizes[1] / D;       // 128
    const int N = in_sizes[0] / F;       // 50000
    const int E = in_sizes[9];           // 800000
    const int T = in_sizes[11] / 3;      // 200000

    const int PD = 512;
    const int GX = (N + 127) / 128;      // 391 row-blocks
    const int Mpad = GX * 128;           // 50048

    float* weights = (float*)d_out;          // [T]
    float* emb     = (float*)d_out + T;      // [N*D]

    // workspace layout (16B-aligned chunks first)
    char* p = (char*)d_ws;
    unsigned short* fs16 = (unsigned short*)p;  p += (size_t)N * 128 * 2;        // 12.8 MB
    unsigned short* g16  = (unsigned short*)p;  p += (size_t)Mpad * 128 * 2;     // 12.8 MB
    unsigned short* Bt   = (unsigned short*)p;  p += (size_t)PD * 128 * 2;       // 128 KB
    float* Wc   = (float*)p;  p += (size_t)F * D * 4;                            // 256 KB
    float* bc   = (float*)p;  p += 512 * 4;
    float* bcp  = (float*)p;  p += PD * 4;
    float* bgp  = (float*)p;  p += PD * 4;
    float* v1p  = (float*)p;  p += PD * 4;
    float* v2p  = (float*)p;  p += PD * 4;
    float* v    = (float*)p;  p += 1024 * 4;
    float* bdot = (float*)p;  p += 16;
    float* ns   = (float*)p;  p += (size_t)N * 4;
    float* nd   = (float*)p;  p += (size_t)N * 4;
    float* h    = (float*)p;  p += (size_t)Mpad * 4;
    float* u1   = (float*)p;  p += (size_t)N * 4;
    float* u2   = (float*)p;  p += (size_t)N * 4;
    unsigned* outd = (unsigned*)p;  p += (size_t)N * 4;
    unsigned* ind  = (unsigned*)p;  p += (size_t)N * 4;
    int* row_ptr = (int*)p;  p += (size_t)(N + 1) * 4;
    int* cursor  = (int*)p;  p += (size_t)N * 4;
    int* csr_src = (int*)p;  p += (size_t)E * 4;

    // zero: degree counters, u-accumulators, g16/h pad rows (deterministic OOB rows)
    hipMemsetAsync(outd, 0, 2 * (size_t)N * sizeof(unsigned), stream);
    hipMemsetAsync(u1, 0, 2 * (size_t)N * sizeof(float), stream);
    hipMemsetAsync(g16 + (size_t)N * 128, 0, (size_t)(Mpad - N) * 128 * 2, stream);
    hipMemsetAsync(h + N, 0, (size_t)(Mpad - N) * 4, stream);

    // degrees + norms + CSR build
    degree_kernel<<<(E + 255) / 256, 256, 0, stream>>>(src, dst, outd, ind, E);
    norm_kernel<<<(N + 255) / 256, 256, 0, stream>>>(outd, ind, ns, nd, N);
    scan_kernel<<<1, 1024, 0, stream>>>(ind, row_ptr, cursor, N);
    csr_fill_kernel<<<(E + 255) / 256, 256, 0, stream>>>(src, dst, cursor, csr_src, E);

    // pred linearization + weight prep
    vcomb_kernel<<<(2 * D + 3) / 4, 256, 0, stream>>>(W_pred_in, W_pred_out, v, D, 2 * D);
    bias_dot_kernel<<<1, 256, 0, stream>>>(b_pred_in, W_pred_out, b_pred_out, bdot, D);

    // Wc = W_aff @ W_gcn ; bc = b_aff @ W_gcn ; pads ; Bt (bf16 transposed Wc)
    {
        dim3 grid((F + 63) / 64, (D + 63) / 64);
        sgemm_kernel<<<grid, 256, 0, stream>>>(W_aff, D, W_gcn, D, Wc, D, F, D, D);
    }
    bcomb_kernel<<<(D + 255) / 256, 256, 0, stream>>>(b_aff, W_gcn, bc, D);
    pad_kernel<<<(PD + 255) / 256, 256, 0, stream>>>(bc, b_gcn, v, bcp, bgp, v1p, v2p, D, PD);
    conv_Bt_kernel<<<(PD * 16 + 255) / 256, 256, 0, stream>>>(Wc, Bt, D, PD);

    // fs16 = bf16(ns ⊙ feats)
    conv_feats_kernel<<<(N * 16 + 255) / 256, 256, 0, stream>>>(feats, ns, fs16, N);

    // feature-space gather: g16, h
    gather_feats_kernel<<<(N + 3) / 4, 256, 0, stream>>>(fs16, csr_src, row_ptr, ns, g16, h, N);

    // MFMA GEMM: emb (+ fused u1/u2 dots)
    {
        dim3 grid(GX, PD / 128);
        gcn_gemm_kernel<<<grid, 256, 0, stream>>>(g16, Bt, h, nd, bcp, bgp, v1p, v2p,
                                                  emb, u1, u2, N, D);
    }

    // weights from per-node scalars
    weights_kernel<<<(T + 255) / 256, 256, 0, stream>>>(trip, u1, u2, bdot, weights, T);
}